// Round 3
// baseline (5494.696 us; speedup 1.0000x reference)
//
#include <hip/hip_runtime.h>
#include <cstdint>
#include <cstddef>

// Problem constants
#define B_       2
#define LSEQ     4096
#define DMODEL   2048
#define NH       32
#define PDIM     64
#define NSTATE   128
#define KCONV    4
#define INTER    2048        // NH*PDIM
#define CONV_DIM 2304       // INTER + 2*NSTATE
#define PROJ_DIM 4384       // INTER + CONV_DIM + NH
#define HBCDT    2336       // CONV_DIM + NH  (hBC | dt slice of proj)
#define ROWS     (B_*LSEQ)  // 8192

__device__ __forceinline__ float siluf(float x) {
  return x / (1.0f + __expf(-x));
}

__device__ __forceinline__ float bf2f(unsigned short u) {
  union { unsigned int i; float f; } v; v.i = ((unsigned int)u) << 16; return v.f;
}
__device__ __forceinline__ unsigned short f2bf(float f) {
  union { float f; unsigned int i; } v; v.f = f;
  unsigned int r = v.i + 0x7fff + ((v.i >> 16) & 1);   // RNE
  return (unsigned short)(r >> 16);
}

// ---------------------------------------------------------------------------
// Generic fp32 NT GEMM: C[m,n] = sum_k A[m,k] * B[n,k]
// A: M x K row-major, B: N x K row-major, C: M x N row-major (stride ldc).
// 64x64 tile, BK=16, 4x4 per thread. M % 64 == 0, K % 16 == 0; N ragged ok.
// ---------------------------------------------------------------------------
__global__ __launch_bounds__(256) void sgemm_nt(
    const float* __restrict__ A, const float* __restrict__ Bm,
    float* __restrict__ C, int M, int N, int K, int ldc) {
  __shared__ float As[16][68];
  __shared__ float Bs[16][68];
  const int t  = threadIdx.x;
  const int m0 = blockIdx.y * 64;
  const int n0 = blockIdx.x * 64;
  const int lr = t >> 2;          // 0..63
  const int lk = (t & 3) * 4;     // k offset (float4)
  const int tx = t & 15;
  const int ty = t >> 4;
  float acc[4][4] = {};

  const float* Aptr = A + (size_t)(m0 + lr) * K + lk;
  const float* Bptr = Bm + (size_t)(n0 + lr) * K + lk;
  const bool bvalid = (n0 + lr) < N;

  for (int k0 = 0; k0 < K; k0 += 16) {
    float4 a4 = *(const float4*)(Aptr + k0);
    float4 b4 = make_float4(0.f, 0.f, 0.f, 0.f);
    if (bvalid) b4 = *(const float4*)(Bptr + k0);
    __syncthreads();
    As[lk+0][lr] = a4.x; As[lk+1][lr] = a4.y; As[lk+2][lr] = a4.z; As[lk+3][lr] = a4.w;
    Bs[lk+0][lr] = b4.x; Bs[lk+1][lr] = b4.y; Bs[lk+2][lr] = b4.z; Bs[lk+3][lr] = b4.w;
    __syncthreads();
#pragma unroll
    for (int kk = 0; kk < 16; ++kk) {
      float4 ra = *(const float4*)(&As[kk][ty * 4]);
      float4 rb = *(const float4*)(&Bs[kk][tx * 4]);
      float av[4] = {ra.x, ra.y, ra.z, ra.w};
      float bv[4] = {rb.x, rb.y, rb.z, rb.w};
#pragma unroll
      for (int i = 0; i < 4; ++i)
#pragma unroll
        for (int j = 0; j < 4; ++j)
          acc[i][j] = fmaf(av[i], bv[j], acc[i][j]);
    }
  }

#pragma unroll
  for (int i = 0; i < 4; ++i) {
    const int m = m0 + ty * 4 + i;
#pragma unroll
    for (int j = 0; j < 4; ++j) {
      const int n = n0 + tx * 4 + j;
      if (n < N) C[(size_t)m * ldc + n] = acc[i][j];
    }
  }
}

// ---------------------------------------------------------------------------
// Depthwise causal conv1d (K=4) + bias + SiLU over hBC_dt (fp32, ld=2336).
// Output convo is bf16, ld=2304.
// ---------------------------------------------------------------------------
__global__ __launch_bounds__(256) void conv_silu_kernel(
    const float* __restrict__ hbcdt, const float* __restrict__ conv_w,
    const float* __restrict__ conv_b, unsigned short* __restrict__ convo) {
  const int idx = blockIdx.x * 256 + threadIdx.x;
  const int total = ROWS * CONV_DIM;
  if (idx >= total) return;
  const int c   = idx % CONV_DIM;
  const int row = idx / CONV_DIM;     // b*L + l
  const int l   = row & (LSEQ - 1);
  float acc = conv_b[c];
  const float* w = conv_w + c * KCONV;
#pragma unroll
  for (int k = 0; k < KCONV; ++k) {
    const int tt = l + k - (KCONV - 1);
    if (tt >= 0)
      acc = fmaf(hbcdt[(size_t)(row + k - (KCONV - 1)) * HBCDT + c], w[k], acc);
  }
  convo[idx] = f2bf(siluf(acc));
}

// ---------------------------------------------------------------------------
// dt = softplus(dt_raw + dt_bias); dA = exp(-exp(A_log)*dt)
// dt_raw is the last 32 columns of hBC_dt.
// ---------------------------------------------------------------------------
__global__ __launch_bounds__(256) void dtprep_kernel(
    const float* __restrict__ hbcdt, const float* __restrict__ dt_bias,
    const float* __restrict__ A_log, float* __restrict__ dt_s,
    float* __restrict__ dA_s) {
  const int idx = blockIdx.x * 256 + threadIdx.x;
  if (idx >= ROWS * NH) return;
  const int h   = idx & (NH - 1);
  const int row = idx >> 5;   // NH == 32
  float x = hbcdt[(size_t)row * HBCDT + CONV_DIM + h] + dt_bias[h];
  float dtv = (x > 20.f) ? x : log1pf(__expf(x));
  dt_s[idx] = dtv;
  dA_s[idx] = __expf(-__expf(A_log[h]) * dtv);
}

// ---------------------------------------------------------------------------
// Sequential selective scan. Grid: B*NH*(PDIM/8) = 512 blocks x 256 threads.
// Thread t: p_local = t>>5, nc = t&31 owns n in [nc*4, nc*4+4).
// convo is bf16. State fp32 in registers. y reduced via shfl_xor (32 lanes).
// ---------------------------------------------------------------------------
__global__ __launch_bounds__(256) void scan_kernel(
    const unsigned short* __restrict__ convo, const float* __restrict__ dt_s,
    const float* __restrict__ dA_s, const float* __restrict__ D_param,
    float* __restrict__ ybuf) {
  const int blk = blockIdx.x;              // [0, 512)
  const int b   = blk >> 8;
  const int rem = blk & 255;
  const int h   = rem >> 3;                // [0,32)
  const int pc  = rem & 7;                 // [0,8)
  const int t   = threadIdx.x;
  const int p_local = t >> 5;              // [0,8)
  const int nc  = t & 31;                  // [0,32)
  const int n0  = nc * 4;
  const int p   = pc * 8 + p_local;

  const float Dh = D_param[h];
  const unsigned short* base = convo + (size_t)b * LSEQ * CONV_DIM;
  const int xoff = h * PDIM + p;

  float s0 = 0.f, s1 = 0.f, s2 = 0.f, s3 = 0.f;

  for (int tt = 0; tt < LSEQ; ++tt) {
    const unsigned short* row = base + (size_t)tt * CONV_DIM;
    const float x = bf2f(row[xoff]);
    const ushort4 Bu = *(const ushort4*)(row + INTER + n0);
    const ushort4 Cu = *(const ushort4*)(row + INTER + NSTATE + n0);
    const int ih = (b * LSEQ + tt) * NH + h;
    const float dtv = dt_s[ih];
    const float dAv = dA_s[ih];
    const float dtx = dtv * x;

    s0 = fmaf(dAv, s0, dtx * bf2f(Bu.x));
    s1 = fmaf(dAv, s1, dtx * bf2f(Bu.y));
    s2 = fmaf(dAv, s2, dtx * bf2f(Bu.z));
    s3 = fmaf(dAv, s3, dtx * bf2f(Bu.w));

    float acc = s0 * bf2f(Cu.x) + s1 * bf2f(Cu.y)
              + s2 * bf2f(Cu.z) + s3 * bf2f(Cu.w);
    acc += __shfl_xor(acc, 16);
    acc += __shfl_xor(acc, 8);
    acc += __shfl_xor(acc, 4);
    acc += __shfl_xor(acc, 2);
    acc += __shfl_xor(acc, 1);
    if (nc == 0)
      ybuf[(size_t)(b * LSEQ + tt) * INTER + h * PDIM + p] = acc + Dh * x;
  }
}

// ---------------------------------------------------------------------------
// Gated RMSNorm: g = y * silu(gate); g *= rsqrt(mean(g^2)+eps) * norm_w.
// One block per (b,l) row; in-place on ybuf. gate lives in d_out (ld=2048).
// ---------------------------------------------------------------------------
__global__ __launch_bounds__(256) void gated_rmsnorm_kernel(
    float* __restrict__ y, const float* __restrict__ gate,
    const float* __restrict__ norm_w) {
  const int row = blockIdx.x;
  float* yr = y + (size_t)row * INTER;
  const float* gr = gate + (size_t)row * INTER;
  const int t = threadIdx.x;
  const int i0 = t * 4;
  const int i1 = t * 4 + 1024;

  float4 y0 = *(const float4*)(yr + i0);
  float4 y1 = *(const float4*)(yr + i1);
  float4 a0 = *(const float4*)(gr + i0);
  float4 a1 = *(const float4*)(gr + i1);

  float g0x = y0.x * siluf(a0.x), g0y = y0.y * siluf(a0.y);
  float g0z = y0.z * siluf(a0.z), g0w = y0.w * siluf(a0.w);
  float g1x = y1.x * siluf(a1.x), g1y = y1.y * siluf(a1.y);
  float g1z = y1.z * siluf(a1.z), g1w = y1.w * siluf(a1.w);

  float ss = g0x*g0x + g0y*g0y + g0z*g0z + g0w*g0w
           + g1x*g1x + g1y*g1y + g1z*g1z + g1w*g1w;

  ss += __shfl_xor(ss, 32);
  ss += __shfl_xor(ss, 16);
  ss += __shfl_xor(ss, 8);
  ss += __shfl_xor(ss, 4);
  ss += __shfl_xor(ss, 2);
  ss += __shfl_xor(ss, 1);

  __shared__ float red[4];
  if ((t & 63) == 0) red[t >> 6] = ss;
  __syncthreads();
  const float tot = red[0] + red[1] + red[2] + red[3];
  const float scale = rsqrtf(tot * (1.0f / INTER) + 1e-5f);

  float4 w0 = *(const float4*)(norm_w + i0);
  float4 w1 = *(const float4*)(norm_w + i1);
  *(float4*)(yr + i0) = make_float4(g0x * scale * w0.x, g0y * scale * w0.y,
                                    g0z * scale * w0.z, g0w * scale * w0.w);
  *(float4*)(yr + i1) = make_float4(g1x * scale * w1.x, g1y * scale * w1.y,
                                    g1z * scale * w1.z, g1w * scale * w1.w);
}

// ---------------------------------------------------------------------------
// Workspace layout (bytes):
//   bufA : ROWS*HBCDT fp32   = 76,546,048   (hBC_dt; later aliased by ybuf fp32)
//   convo: ROWS*CONV_DIM bf16 = 37,748,736
//   dt_s : ROWS*NH fp32       = 1,048,576
//   dA_s : ROWS*NH fp32       = 1,048,576
//   total ≈ 116.4 MB.  gate (fp32 67MB) lives in d_out until GEMM2 overwrites.
// ---------------------------------------------------------------------------
extern "C" void kernel_launch(void* const* d_in, const int* in_sizes, int n_in,
                              void* d_out, int out_size, void* d_ws, size_t ws_size,
                              hipStream_t stream) {
  const float* hs      = (const float*)d_in[0];  // (B,L,DMODEL)
  const float* W_in    = (const float*)d_in[1];  // (PROJ, DMODEL)
  const float* conv_w  = (const float*)d_in[2];  // (CONV_DIM, K)
  const float* conv_b  = (const float*)d_in[3];  // (CONV_DIM)
  const float* dt_bias = (const float*)d_in[4];  // (NH)
  const float* A_log   = (const float*)d_in[5];  // (NH)
  const float* D_param = (const float*)d_in[6];  // (NH)
  const float* norm_w  = (const float*)d_in[7];  // (INTER)
  const float* W_out   = (const float*)d_in[8];  // (DMODEL, INTER)
  float* out = (float*)d_out;

  char* ws = (char*)d_ws;
  float*          bufA  = (float*)ws;                                   // hBC_dt -> ybuf
  unsigned short* convo = (unsigned short*)(ws + (size_t)ROWS * HBCDT * 4);
  float*          dt_s  = (float*)(ws + (size_t)ROWS * HBCDT * 4 + (size_t)ROWS * CONV_DIM * 2);
  float*          dA_s  = dt_s + (size_t)ROWS * NH;
  float*          ybuf  = bufA;                                         // alias (dead hBC_dt)
  float*          gate  = out;                                          // d_out as scratch

  // 1a. hBC_dt = hs @ W_in[2048:4384]^T   (N=2336, ldc=2336)
  {
    dim3 grid((HBCDT + 63) / 64, ROWS / 64);
    sgemm_nt<<<grid, 256, 0, stream>>>(hs, W_in + (size_t)INTER * DMODEL, bufA,
                                       ROWS, HBCDT, DMODEL, HBCDT);
  }
  // 1b. gate = hs @ W_in[0:2048]^T  -> d_out (ldc=2048)
  {
    dim3 grid(INTER / 64, ROWS / 64);
    sgemm_nt<<<grid, 256, 0, stream>>>(hs, W_in, gate, ROWS, INTER, DMODEL, INTER);
  }
  // 2. conv + silu -> convo (bf16)
  {
    const int total = ROWS * CONV_DIM;
    conv_silu_kernel<<<(total + 255) / 256, 256, 0, stream>>>(bufA, conv_w, conv_b, convo);
  }
  // 3. dt / dA
  {
    const int total = ROWS * NH;
    dtprep_kernel<<<(total + 255) / 256, 256, 0, stream>>>(bufA, dt_bias, A_log, dt_s, dA_s);
  }
  // 4. scan -> ybuf (aliases bufA; hBC_dt fully consumed by steps 2-3)
  scan_kernel<<<B_ * NH * (PDIM / 8), 256, 0, stream>>>(convo, dt_s, dA_s, D_param, ybuf);
  // 5. gated rmsnorm (in-place on ybuf, gate from d_out)
  gated_rmsnorm_kernel<<<ROWS, 256, 0, stream>>>(ybuf, gate, norm_w);
  // 6. out = g @ W_out^T  (overwrites d_out, ldc=DMODEL)
  {
    dim3 grid(DMODEL / 64, ROWS / 64);
    sgemm_nt<<<grid, 256, 0, stream>>>(ybuf, W_out, out, ROWS, DMODEL, INTER, DMODEL);
  }
}

// Round 4
// 2045.522 us; speedup vs baseline: 2.6862x; 2.6862x over previous
//
#include <hip/hip_runtime.h>
#include <cstdint>
#include <cstddef>

// Problem constants
#define B_        2
#define LSEQ      4096
#define DMODEL    2048
#define NH        32
#define PDIM      64
#define NSTATE    128
#define KCONV     4
#define INTER     2048       // NH*PDIM
#define CONV_DIM  2304       // INTER + 2*NSTATE
#define HBCDT     2336       // CONV_DIM + NH
#define HBCDT_PAD 2432       // padded to 19*128 for GEMM tiling
#define ROWS      (B_*LSEQ)  // 8192

typedef unsigned short ushort_t;
typedef short bf16x8 __attribute__((ext_vector_type(8)));
typedef float f32x4 __attribute__((ext_vector_type(4)));

__device__ __forceinline__ float siluf(float x) {
  return x / (1.0f + __expf(-x));
}
__device__ __forceinline__ float bf2f(ushort_t u) {
  union { unsigned int i; float f; } v; v.i = ((unsigned int)u) << 16; return v.f;
}
__device__ __forceinline__ ushort_t f2bf(float f) {
  union { float f; unsigned int i; } v; v.f = f;
  unsigned int r = v.i + 0x7fff + ((v.i >> 16) & 1);   // RNE
  return (ushort_t)(r >> 16);
}
__device__ __forceinline__ void async16(const void* g, void* l) {
  __builtin_amdgcn_global_load_lds(
      (const __attribute__((address_space(1))) unsigned int*)g,
      (__attribute__((address_space(3))) unsigned int*)l, 16, 0, 0);
}

// ---------------------------------------------------------------------------
// fp32 -> bf16 conversions
// ---------------------------------------------------------------------------
__global__ __launch_bounds__(256) void cvt_f32_bf16(
    const float* __restrict__ src, ushort_t* __restrict__ dst, int n) {
  const int i = (blockIdx.x * 256 + threadIdx.x) * 4;
  if (i >= n) return;
  float4 v = *(const float4*)(src + i);
  ushort4 o; o.x = f2bf(v.x); o.y = f2bf(v.y); o.z = f2bf(v.z); o.w = f2bf(v.w);
  *(ushort4*)(dst + i) = o;
}

// W_in rows [INTER, INTER+HBCDT) -> bf16 padded to HBCDT_PAD rows (zeros)
__global__ __launch_bounds__(256) void cvt_Wh(
    const float* __restrict__ W_in, ushort_t* __restrict__ dst) {
  const int i = (blockIdx.x * 256 + threadIdx.x) * 4;
  if (i >= HBCDT_PAD * DMODEL) return;
  const int r = i / DMODEL, c = i % DMODEL;
  ushort4 o;
  if (r < HBCDT) {
    float4 v = *(const float4*)(W_in + (size_t)(INTER + r) * DMODEL + c);
    o.x = f2bf(v.x); o.y = f2bf(v.y); o.z = f2bf(v.z); o.w = f2bf(v.w);
  } else {
    o.x = 0; o.y = 0; o.z = 0; o.w = 0;
  }
  *(ushort4*)(dst + i) = o;
}

// ---------------------------------------------------------------------------
// bf16 NT MFMA GEMM: C[m,n] = sum_k A[m,k]*B[n,k].
// A: M x K bf16 row-major, B: N x K bf16 row-major. 128x128 tile, BK=32,
// 256 thr = 4 waves (2x2), each wave 64x64 = 4x4 MFMA 16x16x32 tiles.
// Staging: global_load_lds dwordx4 (wave-uniform LDS base + lane*16).
// M%128==0, N%128==0, K%32==0.
// Fragment layouts (verified m89/m91): A/B lane holds [m|n=lane&15][k=(lane>>4)*8+j];
// C/D: row=(lane>>4)*4+reg, col=lane&15.
// ---------------------------------------------------------------------------
template <bool OUT_BF16>
__global__ __launch_bounds__(256) void gemm_bf16_nt(
    const ushort_t* __restrict__ A, const ushort_t* __restrict__ B,
    void* __restrict__ C, int M, int N, int K, int ldc) {
  __shared__ __align__(16) char smem[16384];
  char* As = smem;            // [128][32] bf16, row stride 64 B
  char* Bs = smem + 8192;
  const int t    = threadIdx.x;
  const int lane = t & 63;
  const int wave = t >> 6;
  const int m0 = blockIdx.y * 128;
  const int n0 = blockIdx.x * 128;
  const int wm = wave & 1;
  const int wn = wave >> 1;

  f32x4 acc[4][4];
#pragma unroll
  for (int i = 0; i < 4; ++i)
#pragma unroll
    for (int j = 0; j < 4; ++j) {
      f32x4 z = {0.f, 0.f, 0.f, 0.f};
      acc[i][j] = z;
    }

  // staging addresses: wave handles rows [wave*32, wave*32+32)
  const int rowW   = wave * 32;
  const int lrow   = lane >> 2;     // 0..15
  const int lchunk = lane & 3;      // 16B chunk within row
  const ushort_t* Ag0 = A + (size_t)(m0 + rowW + lrow) * K + lchunk * 8;
  const ushort_t* Ag1 = Ag0 + (size_t)16 * K;
  const ushort_t* Bg0 = B + (size_t)(n0 + rowW + lrow) * K + lchunk * 8;
  const ushort_t* Bg1 = Bg0 + (size_t)16 * K;
  char* lA0 = As + rowW * 64;
  char* lA1 = As + (rowW + 16) * 64;
  char* lB0 = Bs + rowW * 64;
  char* lB1 = Bs + (rowW + 16) * 64;

  const int rA = wm * 64 + (lane & 15);   // A row for frag reads
  const int rB = wn * 64 + (lane & 15);
  const int kq = (lane >> 4) * 16;        // byte offset of k-quad

  for (int k0 = 0; k0 < K; k0 += 32) {
    async16(Ag0 + k0, lA0);
    async16(Ag1 + k0, lA1);
    async16(Bg0 + k0, lB0);
    async16(Bg1 + k0, lB1);
    __syncthreads();          // drains vmcnt -> LDS ready

    bf16x8 af[4], bfr[4];
#pragma unroll
    for (int i = 0; i < 4; ++i) {
      af[i]  = *(const bf16x8*)(As + (rA + i * 16) * 64 + kq);
      bfr[i] = *(const bf16x8*)(Bs + (rB + i * 16) * 64 + kq);
    }
#pragma unroll
    for (int i = 0; i < 4; ++i)
#pragma unroll
      for (int j = 0; j < 4; ++j)
        acc[i][j] = __builtin_amdgcn_mfma_f32_16x16x32_bf16(
            af[i], bfr[j], acc[i][j], 0, 0, 0);
    __syncthreads();          // all waves done reading before next stage
  }

  const int mbase = m0 + wm * 64 + (lane >> 4) * 4;
  const int nbase = n0 + wn * 64 + (lane & 15);
#pragma unroll
  for (int i = 0; i < 4; ++i)
#pragma unroll
    for (int j = 0; j < 4; ++j)
#pragma unroll
      for (int r = 0; r < 4; ++r) {
        const int m = mbase + i * 16 + r;
        const int n = nbase + j * 16;
        const float v = acc[i][j][r];
        if (OUT_BF16)
          ((ushort_t*)C)[(size_t)m * ldc + n] = f2bf(v);
        else
          ((float*)C)[(size_t)m * ldc + n] = v;
      }
}

// ---------------------------------------------------------------------------
// Depthwise causal conv1d (K=4) + bias + SiLU. Input hbcdt bf16 (ld 2432),
// output convo bf16 (ld 2304).
// ---------------------------------------------------------------------------
__global__ __launch_bounds__(256) void conv_silu_kernel(
    const ushort_t* __restrict__ hbcdt, const float* __restrict__ conv_w,
    const float* __restrict__ conv_b, ushort_t* __restrict__ convo) {
  const int idx = blockIdx.x * 256 + threadIdx.x;
  if (idx >= ROWS * CONV_DIM) return;
  const int c   = idx % CONV_DIM;
  const int row = idx / CONV_DIM;
  const int l   = row & (LSEQ - 1);
  float acc = conv_b[c];
  const float* w = conv_w + c * KCONV;
#pragma unroll
  for (int k = 0; k < KCONV; ++k) {
    const int tt = l + k - (KCONV - 1);
    if (tt >= 0)
      acc = fmaf(bf2f(hbcdt[(size_t)(row + k - (KCONV - 1)) * HBCDT_PAD + c]), w[k], acc);
  }
  convo[idx] = f2bf(siluf(acc));
}

// ---------------------------------------------------------------------------
// dt = softplus(dt_raw + dt_bias); dA = exp(-exp(A_log)*dt)
// ---------------------------------------------------------------------------
__global__ __launch_bounds__(256) void dtprep_kernel(
    const ushort_t* __restrict__ hbcdt, const float* __restrict__ dt_bias,
    const float* __restrict__ A_log, float* __restrict__ dt_s,
    float* __restrict__ dA_s) {
  const int idx = blockIdx.x * 256 + threadIdx.x;
  if (idx >= ROWS * NH) return;
  const int h   = idx & (NH - 1);
  const int row = idx >> 5;
  float x = bf2f(hbcdt[(size_t)row * HBCDT_PAD + CONV_DIM + h]) + dt_bias[h];
  float dtv = (x > 20.f) ? x : log1pf(__expf(x));
  dt_s[idx] = dtv;
  dA_s[idx] = __expf(-__expf(A_log[h]) * dtv);
}

// ---------------------------------------------------------------------------
// Sequential selective scan, unroll x8 with hoisted loads.
// Grid: B*NH*(PDIM/8) = 512 blocks x 256 thr. Thread t: p_local=t>>5, nc=t&31
// owns n in [nc*4, nc*4+4). Output ybuf bf16.
// ---------------------------------------------------------------------------
#define SU 8
__global__ __launch_bounds__(256) void scan_kernel(
    const ushort_t* __restrict__ convo, const float* __restrict__ dt_s,
    const float* __restrict__ dA_s, const float* __restrict__ D_param,
    ushort_t* __restrict__ ybuf) {
  const int blk = blockIdx.x;
  const int b   = blk >> 8;
  const int rem = blk & 255;
  const int h   = rem >> 3;
  const int pc  = rem & 7;
  const int t   = threadIdx.x;
  const int p_local = t >> 5;
  const int nc  = t & 31;
  const int n0  = nc * 4;
  const int p   = pc * 8 + p_local;

  const float Dh = D_param[h];
  const ushort_t* base = convo + (size_t)b * LSEQ * CONV_DIM;
  const int xoff = h * PDIM + p;

  float s0 = 0.f, s1 = 0.f, s2 = 0.f, s3 = 0.f;

  for (int t0 = 0; t0 < LSEQ; t0 += SU) {
    ushort_t xs[SU];
    ushort4  Bu[SU], Cu[SU];
    float    dts[SU], dAs[SU];
#pragma unroll
    for (int u = 0; u < SU; ++u) {
      const ushort_t* row = base + (size_t)(t0 + u) * CONV_DIM;
      xs[u] = row[xoff];
      Bu[u] = *(const ushort4*)(row + INTER + n0);
      Cu[u] = *(const ushort4*)(row + INTER + NSTATE + n0);
      const int ih = (b * LSEQ + t0 + u) * NH + h;
      dts[u] = dt_s[ih];
      dAs[u] = dA_s[ih];
    }
#pragma unroll
    for (int u = 0; u < SU; ++u) {
      const float x   = bf2f(xs[u]);
      const float dtx = dts[u] * x;
      const float dAv = dAs[u];
      s0 = fmaf(dAv, s0, dtx * bf2f(Bu[u].x));
      s1 = fmaf(dAv, s1, dtx * bf2f(Bu[u].y));
      s2 = fmaf(dAv, s2, dtx * bf2f(Bu[u].z));
      s3 = fmaf(dAv, s3, dtx * bf2f(Bu[u].w));
      float acc = s0 * bf2f(Cu[u].x) + s1 * bf2f(Cu[u].y)
                + s2 * bf2f(Cu[u].z) + s3 * bf2f(Cu[u].w);
      acc += __shfl_xor(acc, 16);
      acc += __shfl_xor(acc, 8);
      acc += __shfl_xor(acc, 4);
      acc += __shfl_xor(acc, 2);
      acc += __shfl_xor(acc, 1);
      if (nc == 0)
        ybuf[(size_t)(b * LSEQ + t0 + u) * INTER + h * PDIM + p] =
            f2bf(acc + Dh * x);
    }
  }
}

// ---------------------------------------------------------------------------
// Gated RMSNorm (bf16 in/out, in-place on y): g = y*silu(gate);
// g *= rsqrt(mean(g^2)+eps)*norm_w. One block per row.
// ---------------------------------------------------------------------------
__global__ __launch_bounds__(256) void gated_rmsnorm_kernel(
    ushort_t* __restrict__ y, const ushort_t* __restrict__ gate,
    const float* __restrict__ norm_w) {
  const int row = blockIdx.x;
  ushort_t* yr = y + (size_t)row * INTER;
  const ushort_t* gr = gate + (size_t)row * INTER;
  const int t  = threadIdx.x;
  const int i0 = t * 8;

  ushort4 ya = *(const ushort4*)(yr + i0);
  ushort4 yb = *(const ushort4*)(yr + i0 + 4);
  ushort4 ga = *(const ushort4*)(gr + i0);
  ushort4 gb = *(const ushort4*)(gr + i0 + 4);

  float g[8];
  g[0] = bf2f(ya.x) * siluf(bf2f(ga.x));
  g[1] = bf2f(ya.y) * siluf(bf2f(ga.y));
  g[2] = bf2f(ya.z) * siluf(bf2f(ga.z));
  g[3] = bf2f(ya.w) * siluf(bf2f(ga.w));
  g[4] = bf2f(yb.x) * siluf(bf2f(gb.x));
  g[5] = bf2f(yb.y) * siluf(bf2f(gb.y));
  g[6] = bf2f(yb.z) * siluf(bf2f(gb.z));
  g[7] = bf2f(yb.w) * siluf(bf2f(gb.w));

  float ss = 0.f;
#pragma unroll
  for (int i = 0; i < 8; ++i) ss += g[i] * g[i];

  ss += __shfl_xor(ss, 32);
  ss += __shfl_xor(ss, 16);
  ss += __shfl_xor(ss, 8);
  ss += __shfl_xor(ss, 4);
  ss += __shfl_xor(ss, 2);
  ss += __shfl_xor(ss, 1);

  __shared__ float red[4];
  if ((t & 63) == 0) red[t >> 6] = ss;
  __syncthreads();
  const float tot = red[0] + red[1] + red[2] + red[3];
  const float scale = rsqrtf(tot * (1.0f / INTER) + 1e-5f);

  ushort4 o0, o1;
  o0.x = f2bf(g[0] * scale * norm_w[i0 + 0]);
  o0.y = f2bf(g[1] * scale * norm_w[i0 + 1]);
  o0.z = f2bf(g[2] * scale * norm_w[i0 + 2]);
  o0.w = f2bf(g[3] * scale * norm_w[i0 + 3]);
  o1.x = f2bf(g[4] * scale * norm_w[i0 + 4]);
  o1.y = f2bf(g[5] * scale * norm_w[i0 + 5]);
  o1.z = f2bf(g[6] * scale * norm_w[i0 + 6]);
  o1.w = f2bf(g[7] * scale * norm_w[i0 + 7]);
  *(ushort4*)(yr + i0)     = o0;
  *(ushort4*)(yr + i0 + 4) = o1;
}

// ---------------------------------------------------------------------------
// Workspace layout (bytes), total ~106.4 MB:
//   hbcdt_bf : 8192*2432*2 = 39,845,888   (GEMM1a out; later aliased by ybuf_bf)
//   convo    : 8192*2304*2 = 37,748,736
//   dt_s/dA_s: 2*1,048,576
//   Wh_bf    : 2432*2048*2 =  9,961,472
//   Wg_bf    : 2048*2048*2 =  8,388,608
//   Wout_bf  : 2048*2048*2 =  8,388,608
// d_out doubles as scratch: [0,33.5MB) gate_bf, [33.5,67MB) hs_bf.
// ---------------------------------------------------------------------------
extern "C" void kernel_launch(void* const* d_in, const int* in_sizes, int n_in,
                              void* d_out, int out_size, void* d_ws, size_t ws_size,
                              hipStream_t stream) {
  const float* hs      = (const float*)d_in[0];
  const float* W_in    = (const float*)d_in[1];
  const float* conv_w  = (const float*)d_in[2];
  const float* conv_b  = (const float*)d_in[3];
  const float* dt_bias = (const float*)d_in[4];
  const float* A_log   = (const float*)d_in[5];
  const float* D_param = (const float*)d_in[6];
  const float* norm_w  = (const float*)d_in[7];
  const float* W_out   = (const float*)d_in[8];
  float* out = (float*)d_out;

  char* ws = (char*)d_ws;
  size_t off = 0;
  ushort_t* hbcdt_bf = (ushort_t*)(ws + off); off += (size_t)ROWS * HBCDT_PAD * 2;
  ushort_t* convo    = (ushort_t*)(ws + off); off += (size_t)ROWS * CONV_DIM * 2;
  float*    dt_s     = (float*)(ws + off);    off += (size_t)ROWS * NH * 4;
  float*    dA_s     = (float*)(ws + off);    off += (size_t)ROWS * NH * 4;
  ushort_t* Wh_bf    = (ushort_t*)(ws + off); off += (size_t)HBCDT_PAD * DMODEL * 2;
  ushort_t* Wg_bf    = (ushort_t*)(ws + off); off += (size_t)DMODEL * DMODEL * 2;
  ushort_t* Wout_bf  = (ushort_t*)(ws + off); off += (size_t)DMODEL * DMODEL * 2;
  ushort_t* ybuf_bf  = hbcdt_bf;                       // alias (hBC_dt dead by then)

  char* outc = (char*)d_out;
  ushort_t* gate_bf = (ushort_t*)outc;                            // 33.5 MB
  ushort_t* hs_bf   = (ushort_t*)(outc + (size_t)ROWS * INTER * 2); // 33.5 MB

  // 0. conversions
  cvt_f32_bf16<<<(ROWS * DMODEL / 4 + 255) / 256, 256, 0, stream>>>(
      hs, hs_bf, ROWS * DMODEL);
  cvt_Wh<<<(HBCDT_PAD * DMODEL / 4 + 255) / 256, 256, 0, stream>>>(W_in, Wh_bf);
  cvt_f32_bf16<<<(DMODEL * DMODEL / 4 + 255) / 256, 256, 0, stream>>>(
      W_in, Wg_bf, DMODEL * DMODEL);
  cvt_f32_bf16<<<(DMODEL * DMODEL / 4 + 255) / 256, 256, 0, stream>>>(
      W_out, Wout_bf, DMODEL * DMODEL);

  // 1a. hBC_dt = hs @ Wh^T  (bf16 out, N=2432 padded)
  {
    dim3 grid(HBCDT_PAD / 128, ROWS / 128);
    gemm_bf16_nt<true><<<grid, 256, 0, stream>>>(
        hs_bf, Wh_bf, hbcdt_bf, ROWS, HBCDT_PAD, DMODEL, HBCDT_PAD);
  }
  // 1b. gate = hs @ Wg^T  (bf16 out -> d_out lower half)
  {
    dim3 grid(INTER / 128, ROWS / 128);
    gemm_bf16_nt<true><<<grid, 256, 0, stream>>>(
        hs_bf, Wg_bf, gate_bf, ROWS, INTER, DMODEL, INTER);
  }
  // 2. conv + silu
  conv_silu_kernel<<<(ROWS * CONV_DIM + 255) / 256, 256, 0, stream>>>(
      hbcdt_bf, conv_w, conv_b, convo);
  // 3. dt / dA
  dtprep_kernel<<<(ROWS * NH + 255) / 256, 256, 0, stream>>>(
      hbcdt_bf, dt_bias, A_log, dt_s, dA_s);
  // 4. scan -> ybuf_bf (aliases hbcdt_bf)
  scan_kernel<<<B_ * NH * (PDIM / 8), 256, 0, stream>>>(
      convo, dt_s, dA_s, D_param, ybuf_bf);
  // 5. gated rmsnorm (in-place on ybuf_bf; gate from d_out)
  gated_rmsnorm_kernel<<<ROWS, 256, 0, stream>>>(ybuf_bf, gate_bf, norm_w);
  // 6. out = g @ W_out^T (fp32 out, overwrites d_out)
  {
    dim3 grid(DMODEL / 128, ROWS / 128);
    gemm_bf16_nt<false><<<grid, 256, 0, stream>>>(
        ybuf_bf, Wout_bf, out, ROWS, DMODEL, INTER, DMODEL);
  }
}

// Round 5
// 1521.715 us; speedup vs baseline: 3.6109x; 1.3442x over previous
//
#include <hip/hip_runtime.h>
#include <cstdint>
#include <cstddef>

// Problem constants
#define B_        2
#define LSEQ      4096
#define DMODEL    2048
#define NH        32
#define PDIM      64
#define NSTATE    128
#define KCONV     4
#define INTER     2048       // NH*PDIM
#define CONV_DIM  2304       // INTER + 2*NSTATE
#define HBCDT     2336       // CONV_DIM + NH
#define HBCDT_PAD 2432       // padded to 19*128 for GEMM tiling
#define ROWS      (B_*LSEQ)  // 8192
#define NC        32         // sequence chunks for the scan
#define CLEN      (LSEQ/NC)  // 128

typedef unsigned short ushort_t;
typedef short bf16x8 __attribute__((ext_vector_type(8)));
typedef float f32x4 __attribute__((ext_vector_type(4)));

__device__ __forceinline__ float siluf(float x) {
  return x / (1.0f + __expf(-x));
}
__device__ __forceinline__ float bf2f(ushort_t u) {
  union { unsigned int i; float f; } v; v.i = ((unsigned int)u) << 16; return v.f;
}
__device__ __forceinline__ ushort_t f2bf(float f) {
  union { float f; unsigned int i; } v; v.f = f;
  unsigned int r = v.i + 0x7fff + ((v.i >> 16) & 1);   // RNE
  return (ushort_t)(r >> 16);
}
__device__ __forceinline__ void async16(const void* g, void* l) {
  __builtin_amdgcn_global_load_lds(
      (const __attribute__((address_space(1))) unsigned int*)g,
      (__attribute__((address_space(3))) unsigned int*)l, 16, 0, 0);
}

// ---------------------------------------------------------------------------
// fp32 -> bf16 conversions
// ---------------------------------------------------------------------------
__global__ __launch_bounds__(256) void cvt_f32_bf16(
    const float* __restrict__ src, ushort_t* __restrict__ dst, int n) {
  const int i = (blockIdx.x * 256 + threadIdx.x) * 4;
  if (i >= n) return;
  float4 v = *(const float4*)(src + i);
  ushort4 o; o.x = f2bf(v.x); o.y = f2bf(v.y); o.z = f2bf(v.z); o.w = f2bf(v.w);
  *(ushort4*)(dst + i) = o;
}

// W_in rows [INTER, INTER+HBCDT) -> bf16 padded to HBCDT_PAD rows (zeros)
__global__ __launch_bounds__(256) void cvt_Wh(
    const float* __restrict__ W_in, ushort_t* __restrict__ dst) {
  const int i = (blockIdx.x * 256 + threadIdx.x) * 4;
  if (i >= HBCDT_PAD * DMODEL) return;
  const int r = i / DMODEL, c = i % DMODEL;
  ushort4 o;
  if (r < HBCDT) {
    float4 v = *(const float4*)(W_in + (size_t)(INTER + r) * DMODEL + c);
    o.x = f2bf(v.x); o.y = f2bf(v.y); o.z = f2bf(v.z); o.w = f2bf(v.w);
  } else {
    o.x = 0; o.y = 0; o.z = 0; o.w = 0;
  }
  *(ushort4*)(dst + i) = o;
}

// ---------------------------------------------------------------------------
// bf16 NT MFMA GEMM: C[m,n] = sum_k A[m,k]*B[n,k]. 128x128 tile, BK=32,
// 4 waves (2x2), each wave 64x64 via 4x4 MFMA 16x16x32 tiles.
// ---------------------------------------------------------------------------
template <bool OUT_BF16>
__global__ __launch_bounds__(256) void gemm_bf16_nt(
    const ushort_t* __restrict__ A, const ushort_t* __restrict__ B,
    void* __restrict__ C, int M, int N, int K, int ldc) {
  __shared__ __align__(16) char smem[16384];
  char* As = smem;            // [128][32] bf16, row stride 64 B
  char* Bs = smem + 8192;
  const int t    = threadIdx.x;
  const int lane = t & 63;
  const int wave = t >> 6;
  const int m0 = blockIdx.y * 128;
  const int n0 = blockIdx.x * 128;
  const int wm = wave & 1;
  const int wn = wave >> 1;

  f32x4 acc[4][4];
#pragma unroll
  for (int i = 0; i < 4; ++i)
#pragma unroll
    for (int j = 0; j < 4; ++j) {
      f32x4 z = {0.f, 0.f, 0.f, 0.f};
      acc[i][j] = z;
    }

  const int rowW   = wave * 32;
  const int lrow   = lane >> 2;
  const int lchunk = lane & 3;
  const ushort_t* Ag0 = A + (size_t)(m0 + rowW + lrow) * K + lchunk * 8;
  const ushort_t* Ag1 = Ag0 + (size_t)16 * K;
  const ushort_t* Bg0 = B + (size_t)(n0 + rowW + lrow) * K + lchunk * 8;
  const ushort_t* Bg1 = Bg0 + (size_t)16 * K;
  char* lA0 = As + rowW * 64;
  char* lA1 = As + (rowW + 16) * 64;
  char* lB0 = Bs + rowW * 64;
  char* lB1 = Bs + (rowW + 16) * 64;

  const int rA = wm * 64 + (lane & 15);
  const int rB = wn * 64 + (lane & 15);
  const int kq = (lane >> 4) * 16;

  for (int k0 = 0; k0 < K; k0 += 32) {
    async16(Ag0 + k0, lA0);
    async16(Ag1 + k0, lA1);
    async16(Bg0 + k0, lB0);
    async16(Bg1 + k0, lB1);
    __syncthreads();

    bf16x8 af[4], bfr[4];
#pragma unroll
    for (int i = 0; i < 4; ++i) {
      af[i]  = *(const bf16x8*)(As + (rA + i * 16) * 64 + kq);
      bfr[i] = *(const bf16x8*)(Bs + (rB + i * 16) * 64 + kq);
    }
#pragma unroll
    for (int i = 0; i < 4; ++i)
#pragma unroll
      for (int j = 0; j < 4; ++j)
        acc[i][j] = __builtin_amdgcn_mfma_f32_16x16x32_bf16(
            af[i], bfr[j], acc[i][j], 0, 0, 0);
    __syncthreads();
  }

  const int mbase = m0 + wm * 64 + (lane >> 4) * 4;
  const int nbase = n0 + wn * 64 + (lane & 15);
#pragma unroll
  for (int i = 0; i < 4; ++i)
#pragma unroll
    for (int j = 0; j < 4; ++j)
#pragma unroll
      for (int r = 0; r < 4; ++r) {
        const int m = mbase + i * 16 + r;
        const int n = nbase + j * 16;
        const float v = acc[i][j][r];
        if (OUT_BF16)
          ((ushort_t*)C)[(size_t)m * ldc + n] = f2bf(v);
        else
          ((float*)C)[(size_t)m * ldc + n] = v;
      }
}

// ---------------------------------------------------------------------------
// Depthwise causal conv1d (K=4) + bias + SiLU. Input hbcdt bf16 (ld 2432),
// output convo bf16 (ld 2304).
// ---------------------------------------------------------------------------
__global__ __launch_bounds__(256) void conv_silu_kernel(
    const ushort_t* __restrict__ hbcdt, const float* __restrict__ conv_w,
    const float* __restrict__ conv_b, ushort_t* __restrict__ convo) {
  const int idx = blockIdx.x * 256 + threadIdx.x;
  if (idx >= ROWS * CONV_DIM) return;
  const int c   = idx % CONV_DIM;
  const int row = idx / CONV_DIM;
  const int l   = row & (LSEQ - 1);
  float acc = conv_b[c];
  const float* w = conv_w + c * KCONV;
#pragma unroll
  for (int k = 0; k < KCONV; ++k) {
    const int tt = l + k - (KCONV - 1);
    if (tt >= 0)
      acc = fmaf(bf2f(hbcdt[(size_t)(row + k - (KCONV - 1)) * HBCDT_PAD + c]), w[k], acc);
  }
  convo[idx] = f2bf(siluf(acc));
}

// ---------------------------------------------------------------------------
// dt = softplus(dt_raw + dt_bias); dA = exp(-exp(A_log)*dt)
// ---------------------------------------------------------------------------
__global__ __launch_bounds__(256) void dtprep_kernel(
    const ushort_t* __restrict__ hbcdt, const float* __restrict__ dt_bias,
    const float* __restrict__ A_log, float* __restrict__ dt_s,
    float* __restrict__ dA_s) {
  const int idx = blockIdx.x * 256 + threadIdx.x;
  if (idx >= ROWS * NH) return;
  const int h   = idx & (NH - 1);
  const int row = idx >> 5;
  float x = bf2f(hbcdt[(size_t)row * HBCDT_PAD + CONV_DIM + h]) + dt_bias[h];
  float dtv = (x > 20.f) ? x : log1pf(__expf(x));
  dt_s[idx] = dtv;
  dA_s[idx] = __expf(-__expf(A_log[h]) * dtv);
}

// ---------------------------------------------------------------------------
// Chunked scan, pass 1: per-chunk local states (h0 = 0), update only.
// Grid: B*NH*8*NC = 16384 blocks x 256 thr.
// Writes Sloc[b][c][h][p][n] (bf16) and chunkA[b][h][c] (fp32, thread 0).
// ---------------------------------------------------------------------------
#define SU 8
__global__ __launch_bounds__(256) void scan_state_kernel(
    const ushort_t* __restrict__ convo, const float* __restrict__ dt_s,
    const float* __restrict__ dA_s, ushort_t* __restrict__ Sbuf,
    float* __restrict__ chunkA) {
  const int blk = blockIdx.x;
  const int c   = blk & (NC - 1);
  const int pc  = (blk >> 5) & 7;
  const int h   = (blk >> 8) & 31;
  const int b   = (blk >> 13) & 1;
  const int t   = threadIdx.x;
  const int p_local = t >> 5;
  const int nc  = t & 31;
  const int n0  = nc * 4;
  const int p   = pc * 8 + p_local;

  const ushort_t* base = convo + (size_t)b * LSEQ * CONV_DIM;
  const int xoff = h * PDIM + p;

  float s0 = 0.f, s1 = 0.f, s2 = 0.f, s3 = 0.f;
  float prodA = 1.f;

  const int tstart = c * CLEN;
  for (int t0 = tstart; t0 < tstart + CLEN; t0 += SU) {
    ushort_t xs[SU];
    ushort4  Bu[SU];
    float    dts[SU], dAs[SU];
#pragma unroll
    for (int u = 0; u < SU; ++u) {
      const ushort_t* row = base + (size_t)(t0 + u) * CONV_DIM;
      xs[u] = row[xoff];
      Bu[u] = *(const ushort4*)(row + INTER + n0);
      const int ih = (b * LSEQ + t0 + u) * NH + h;
      dts[u] = dt_s[ih];
      dAs[u] = dA_s[ih];
    }
#pragma unroll
    for (int u = 0; u < SU; ++u) {
      const float x   = bf2f(xs[u]);
      const float dtx = dts[u] * x;
      const float dAv = dAs[u];
      prodA *= dAv;
      s0 = fmaf(dAv, s0, dtx * bf2f(Bu[u].x));
      s1 = fmaf(dAv, s1, dtx * bf2f(Bu[u].y));
      s2 = fmaf(dAv, s2, dtx * bf2f(Bu[u].z));
      s3 = fmaf(dAv, s3, dtx * bf2f(Bu[u].w));
    }
  }

  ushort4 o;
  o.x = f2bf(s0); o.y = f2bf(s1); o.z = f2bf(s2); o.w = f2bf(s3);
  const size_t soff = ((((size_t)b * NC + c) * NH + h) * PDIM + p) * NSTATE + n0;
  *(ushort4*)(Sbuf + soff) = o;
  if (t == 0) chunkA[(b * NH + h) * NC + c] = prodA;
}

// ---------------------------------------------------------------------------
// Chunked scan, pass 2: in-place serial combine over chunks.
// Thread (b,h,p,nq): for c: Sin_c = S (write), S = chunkA_c*S + Sloc_c.
// 131072 threads = 512 blocks x 256.
// ---------------------------------------------------------------------------
__global__ __launch_bounds__(256) void state_combine_kernel(
    ushort_t* __restrict__ Sbuf, const float* __restrict__ chunkA) {
  const int idx = blockIdx.x * 256 + threadIdx.x;
  const int nq = idx & 31;
  const int p  = (idx >> 5) & 63;
  const int h  = (idx >> 11) & 31;
  const int b  = (idx >> 16) & 1;
  const float* ca = chunkA + (b * NH + h) * NC;

  float s0 = 0.f, s1 = 0.f, s2 = 0.f, s3 = 0.f;
#pragma unroll 4
  for (int c = 0; c < NC; ++c) {
    const size_t off = ((((size_t)b * NC + c) * NH + h) * PDIM + p) * NSTATE + nq * 4;
    ushort4 loc = *(const ushort4*)(Sbuf + off);
    ushort4 o;
    o.x = f2bf(s0); o.y = f2bf(s1); o.z = f2bf(s2); o.w = f2bf(s3);
    *(ushort4*)(Sbuf + off) = o;                 // Sin for chunk c
    const float a = ca[c];
    s0 = fmaf(a, s0, bf2f(loc.x));
    s1 = fmaf(a, s1, bf2f(loc.y));
    s2 = fmaf(a, s2, bf2f(loc.z));
    s3 = fmaf(a, s3, bf2f(loc.w));
  }
}

// ---------------------------------------------------------------------------
// Chunked scan, pass 3: full y recompute per chunk starting from Sin.
// Grid: 16384 blocks x 256 thr (same decomposition as pass 1).
// ---------------------------------------------------------------------------
__global__ __launch_bounds__(256) void scan_y_kernel(
    const ushort_t* __restrict__ convo, const float* __restrict__ dt_s,
    const float* __restrict__ dA_s, const float* __restrict__ D_param,
    const ushort_t* __restrict__ Sbuf, ushort_t* __restrict__ ybuf) {
  const int blk = blockIdx.x;
  const int c   = blk & (NC - 1);
  const int pc  = (blk >> 5) & 7;
  const int h   = (blk >> 8) & 31;
  const int b   = (blk >> 13) & 1;
  const int t   = threadIdx.x;
  const int p_local = t >> 5;
  const int nc  = t & 31;
  const int n0  = nc * 4;
  const int p   = pc * 8 + p_local;

  const float Dh = D_param[h];
  const ushort_t* base = convo + (size_t)b * LSEQ * CONV_DIM;
  const int xoff = h * PDIM + p;

  const size_t soff = ((((size_t)b * NC + c) * NH + h) * PDIM + p) * NSTATE + n0;
  ushort4 si = *(const ushort4*)(Sbuf + soff);
  float s0 = bf2f(si.x), s1 = bf2f(si.y), s2 = bf2f(si.z), s3 = bf2f(si.w);

  const int tstart = c * CLEN;
  for (int t0 = tstart; t0 < tstart + CLEN; t0 += SU) {
    ushort_t xs[SU];
    ushort4  Bu[SU], Cu[SU];
    float    dts[SU], dAs[SU];
#pragma unroll
    for (int u = 0; u < SU; ++u) {
      const ushort_t* row = base + (size_t)(t0 + u) * CONV_DIM;
      xs[u] = row[xoff];
      Bu[u] = *(const ushort4*)(row + INTER + n0);
      Cu[u] = *(const ushort4*)(row + INTER + NSTATE + n0);
      const int ih = (b * LSEQ + t0 + u) * NH + h;
      dts[u] = dt_s[ih];
      dAs[u] = dA_s[ih];
    }
#pragma unroll
    for (int u = 0; u < SU; ++u) {
      const float x   = bf2f(xs[u]);
      const float dtx = dts[u] * x;
      const float dAv = dAs[u];
      s0 = fmaf(dAv, s0, dtx * bf2f(Bu[u].x));
      s1 = fmaf(dAv, s1, dtx * bf2f(Bu[u].y));
      s2 = fmaf(dAv, s2, dtx * bf2f(Bu[u].z));
      s3 = fmaf(dAv, s3, dtx * bf2f(Bu[u].w));
      float acc = s0 * bf2f(Cu[u].x) + s1 * bf2f(Cu[u].y)
                + s2 * bf2f(Cu[u].z) + s3 * bf2f(Cu[u].w);
      acc += __shfl_xor(acc, 16);
      acc += __shfl_xor(acc, 8);
      acc += __shfl_xor(acc, 4);
      acc += __shfl_xor(acc, 2);
      acc += __shfl_xor(acc, 1);
      if (nc == 0)
        ybuf[(size_t)(b * LSEQ + t0 + u) * INTER + h * PDIM + p] =
            f2bf(acc + Dh * x);
    }
  }
}

// ---------------------------------------------------------------------------
// Gated RMSNorm (bf16 in/out, in-place on y).
// ---------------------------------------------------------------------------
__global__ __launch_bounds__(256) void gated_rmsnorm_kernel(
    ushort_t* __restrict__ y, const ushort_t* __restrict__ gate,
    const float* __restrict__ norm_w) {
  const int row = blockIdx.x;
  ushort_t* yr = y + (size_t)row * INTER;
  const ushort_t* gr = gate + (size_t)row * INTER;
  const int t  = threadIdx.x;
  const int i0 = t * 8;

  ushort4 ya = *(const ushort4*)(yr + i0);
  ushort4 yb = *(const ushort4*)(yr + i0 + 4);
  ushort4 ga = *(const ushort4*)(gr + i0);
  ushort4 gb = *(const ushort4*)(gr + i0 + 4);

  float g[8];
  g[0] = bf2f(ya.x) * siluf(bf2f(ga.x));
  g[1] = bf2f(ya.y) * siluf(bf2f(ga.y));
  g[2] = bf2f(ya.z) * siluf(bf2f(ga.z));
  g[3] = bf2f(ya.w) * siluf(bf2f(ga.w));
  g[4] = bf2f(yb.x) * siluf(bf2f(gb.x));
  g[5] = bf2f(yb.y) * siluf(bf2f(gb.y));
  g[6] = bf2f(yb.z) * siluf(bf2f(gb.z));
  g[7] = bf2f(yb.w) * siluf(bf2f(gb.w));

  float ss = 0.f;
#pragma unroll
  for (int i = 0; i < 8; ++i) ss += g[i] * g[i];

  ss += __shfl_xor(ss, 32);
  ss += __shfl_xor(ss, 16);
  ss += __shfl_xor(ss, 8);
  ss += __shfl_xor(ss, 4);
  ss += __shfl_xor(ss, 2);
  ss += __shfl_xor(ss, 1);

  __shared__ float red[4];
  if ((t & 63) == 0) red[t >> 6] = ss;
  __syncthreads();
  const float tot = red[0] + red[1] + red[2] + red[3];
  const float scale = rsqrtf(tot * (1.0f / INTER) + 1e-5f);

  ushort4 o0, o1;
  o0.x = f2bf(g[0] * scale * norm_w[i0 + 0]);
  o0.y = f2bf(g[1] * scale * norm_w[i0 + 1]);
  o0.z = f2bf(g[2] * scale * norm_w[i0 + 2]);
  o0.w = f2bf(g[3] * scale * norm_w[i0 + 3]);
  o1.x = f2bf(g[4] * scale * norm_w[i0 + 4]);
  o1.y = f2bf(g[5] * scale * norm_w[i0 + 5]);
  o1.z = f2bf(g[6] * scale * norm_w[i0 + 6]);
  o1.w = f2bf(g[7] * scale * norm_w[i0 + 7]);
  *(ushort4*)(yr + i0)     = o0;
  *(ushort4*)(yr + i0 + 4) = o1;
}

// ---------------------------------------------------------------------------
// Workspace (~106.4 MB): hbcdt_bf(39.8, aliased by ybuf) | convo(37.7) |
// dt_s/dA_s(2) | Wh_bf(10.0) | Wg_bf(8.4) | Wout_bf(8.4) | chunkA(8KB).
// d_out scratch: [0,33.5MB) gate_bf; [33.5,67MB) hs_bf -> Sbuf (states).
// ---------------------------------------------------------------------------
extern "C" void kernel_launch(void* const* d_in, const int* in_sizes, int n_in,
                              void* d_out, int out_size, void* d_ws, size_t ws_size,
                              hipStream_t stream) {
  const float* hs      = (const float*)d_in[0];
  const float* W_in    = (const float*)d_in[1];
  const float* conv_w  = (const float*)d_in[2];
  const float* conv_b  = (const float*)d_in[3];
  const float* dt_bias = (const float*)d_in[4];
  const float* A_log   = (const float*)d_in[5];
  const float* D_param = (const float*)d_in[6];
  const float* norm_w  = (const float*)d_in[7];
  const float* W_out   = (const float*)d_in[8];
  float* out = (float*)d_out;

  char* ws = (char*)d_ws;
  size_t off = 0;
  ushort_t* hbcdt_bf = (ushort_t*)(ws + off); off += (size_t)ROWS * HBCDT_PAD * 2;
  ushort_t* convo    = (ushort_t*)(ws + off); off += (size_t)ROWS * CONV_DIM * 2;
  float*    dt_s     = (float*)(ws + off);    off += (size_t)ROWS * NH * 4;
  float*    dA_s     = (float*)(ws + off);    off += (size_t)ROWS * NH * 4;
  ushort_t* Wh_bf    = (ushort_t*)(ws + off); off += (size_t)HBCDT_PAD * DMODEL * 2;
  ushort_t* Wg_bf    = (ushort_t*)(ws + off); off += (size_t)DMODEL * DMODEL * 2;
  ushort_t* Wout_bf  = (ushort_t*)(ws + off); off += (size_t)DMODEL * DMODEL * 2;
  float*    chunkA   = (float*)(ws + off);    off += (size_t)B_ * NH * NC * 4;
  ushort_t* ybuf_bf  = hbcdt_bf;                       // alias (hBC_dt dead)

  char* outc = (char*)d_out;
  ushort_t* gate_bf = (ushort_t*)outc;                              // 33.5 MB
  ushort_t* hs_bf   = (ushort_t*)(outc + (size_t)ROWS * INTER * 2); // 33.5 MB
  ushort_t* Sbuf    = hs_bf;   // states overwrite hs_bf after GEMMs consume it

  // 0. conversions
  cvt_f32_bf16<<<(ROWS * DMODEL / 4 + 255) / 256, 256, 0, stream>>>(
      hs, hs_bf, ROWS * DMODEL);
  cvt_Wh<<<(HBCDT_PAD * DMODEL / 4 + 255) / 256, 256, 0, stream>>>(W_in, Wh_bf);
  cvt_f32_bf16<<<(DMODEL * DMODEL / 4 + 255) / 256, 256, 0, stream>>>(
      W_in, Wg_bf, DMODEL * DMODEL);
  cvt_f32_bf16<<<(DMODEL * DMODEL / 4 + 255) / 256, 256, 0, stream>>>(
      W_out, Wout_bf, DMODEL * DMODEL);

  // 1a. hBC_dt = hs @ Wh^T
  {
    dim3 grid(HBCDT_PAD / 128, ROWS / 128);
    gemm_bf16_nt<true><<<grid, 256, 0, stream>>>(
        hs_bf, Wh_bf, hbcdt_bf, ROWS, HBCDT_PAD, DMODEL, HBCDT_PAD);
  }
  // 1b. gate = hs @ Wg^T
  {
    dim3 grid(INTER / 128, ROWS / 128);
    gemm_bf16_nt<true><<<grid, 256, 0, stream>>>(
        hs_bf, Wg_bf, gate_bf, ROWS, INTER, DMODEL, INTER);
  }
  // 2. conv + silu
  conv_silu_kernel<<<(ROWS * CONV_DIM + 255) / 256, 256, 0, stream>>>(
      hbcdt_bf, conv_w, conv_b, convo);
  // 3. dt / dA
  dtprep_kernel<<<(ROWS * NH + 255) / 256, 256, 0, stream>>>(
      hbcdt_bf, dt_bias, A_log, dt_s, dA_s);
  // 4. chunked scan: local states -> combine -> y
  scan_state_kernel<<<B_ * NH * 8 * NC, 256, 0, stream>>>(
      convo, dt_s, dA_s, Sbuf, chunkA);
  state_combine_kernel<<<(B_ * NH * PDIM * (NSTATE / 4)) / 256, 256, 0, stream>>>(
      Sbuf, chunkA);
  scan_y_kernel<<<B_ * NH * 8 * NC, 256, 0, stream>>>(
      convo, dt_s, dA_s, D_param, Sbuf, ybuf_bf);
  // 5. gated rmsnorm (in-place on ybuf_bf)
  gated_rmsnorm_kernel<<<ROWS, 256, 0, stream>>>(ybuf_bf, gate_bf, norm_w);
  // 6. out = g @ W_out^T (fp32, overwrites d_out)
  {
    dim3 grid(DMODEL / 128, ROWS / 128);
    gemm_bf16_nt<false><<<grid, 256, 0, stream>>>(
        ybuf_bf, Wout_bf, out, ROWS, DMODEL, INTER, DMODEL);
  }
}

// Round 7
// 980.321 us; speedup vs baseline: 5.6050x; 1.5523x over previous
//
#include <hip/hip_runtime.h>
#include <cstdint>
#include <cstddef>

// Problem constants
#define B_        2
#define LSEQ      4096
#define DMODEL    2048
#define NH        32
#define PDIM      64
#define NSTATE    128
#define KCONV     4
#define INTER     2048       // NH*PDIM
#define CONV_DIM  2304       // INTER + 2*NSTATE
#define HBCDT     2336       // CONV_DIM + NH
#define HBCDT_PAD 2432       // padded to 19*128 for GEMM tiling
#define ROWS      (B_*LSEQ)  // 8192
#define NC        32         // sequence chunks for the scan
#define CLEN      (LSEQ/NC)  // 128  (= Q)

typedef unsigned short ushort_t;
typedef short bf16x8 __attribute__((ext_vector_type(8)));
typedef float f32x4 __attribute__((ext_vector_type(4)));

__device__ __forceinline__ float siluf(float x) {
  return x / (1.0f + __expf(-x));
}
__device__ __forceinline__ float bf2f(ushort_t u) {
  union { unsigned int i; float f; } v; v.i = ((unsigned int)u) << 16; return v.f;
}
__device__ __forceinline__ ushort_t f2bf(float f) {
  union { float f; unsigned int i; } v; v.f = f;
  unsigned int r = v.i + 0x7fff + ((v.i >> 16) & 1);   // RNE
  return (ushort_t)(r >> 16);
}
__device__ __forceinline__ void async16(const void* g, void* l) {
  __builtin_amdgcn_global_load_lds(
      (const __attribute__((address_space(1))) unsigned int*)g,
      (__attribute__((address_space(3))) unsigned int*)l, 16, 0, 0);
}

// ---------------------------------------------------------------------------
// fp32 -> bf16 conversions
// ---------------------------------------------------------------------------
__global__ __launch_bounds__(256) void cvt_f32_bf16(
    const float* __restrict__ src, ushort_t* __restrict__ dst, int n) {
  const int i = (blockIdx.x * 256 + threadIdx.x) * 4;
  if (i >= n) return;
  float4 v = *(const float4*)(src + i);
  ushort4 o; o.x = f2bf(v.x); o.y = f2bf(v.y); o.z = f2bf(v.z); o.w = f2bf(v.w);
  *(ushort4*)(dst + i) = o;
}

// W_in rows [INTER, INTER+HBCDT) -> bf16 padded to HBCDT_PAD rows (zeros)
__global__ __launch_bounds__(256) void cvt_Wh(
    const float* __restrict__ W_in, ushort_t* __restrict__ dst) {
  const int i = (blockIdx.x * 256 + threadIdx.x) * 4;
  if (i >= HBCDT_PAD * DMODEL) return;
  const int r = i / DMODEL, c = i % DMODEL;
  ushort4 o;
  if (r < HBCDT) {
    float4 v = *(const float4*)(W_in + (size_t)(INTER + r) * DMODEL + c);
    o.x = f2bf(v.x); o.y = f2bf(v.y); o.z = f2bf(v.z); o.w = f2bf(v.w);
  } else {
    o.x = 0; o.y = 0; o.z = 0; o.w = 0;
  }
  *(ushort4*)(dst + i) = o;
}

// ---------------------------------------------------------------------------
// bf16 NT MFMA GEMM: C[m,n] = sum_k A[m,k]*B[n,k]. 128x128 tile, BK=32,
// 4 waves (2x2), each wave 64x64 via 4x4 MFMA 16x16x32 tiles.
// ---------------------------------------------------------------------------
template <bool OUT_BF16>
__global__ __launch_bounds__(256) void gemm_bf16_nt(
    const ushort_t* __restrict__ A, const ushort_t* __restrict__ B,
    void* __restrict__ C, int M, int N, int K, int ldc) {
  __shared__ __align__(16) char smem[16384];
  char* As = smem;            // [128][32] bf16, row stride 64 B
  char* Bs = smem + 8192;
  const int t    = threadIdx.x;
  const int lane = t & 63;
  const int wave = t >> 6;
  const int m0 = blockIdx.y * 128;
  const int n0 = blockIdx.x * 128;
  const int wm = wave & 1;
  const int wn = wave >> 1;

  f32x4 acc[4][4];
#pragma unroll
  for (int i = 0; i < 4; ++i)
#pragma unroll
    for (int j = 0; j < 4; ++j) {
      f32x4 z = {0.f, 0.f, 0.f, 0.f};
      acc[i][j] = z;
    }

  const int rowW   = wave * 32;
  const int lrow   = lane >> 2;
  const int lchunk = lane & 3;
  const ushort_t* Ag0 = A + (size_t)(m0 + rowW + lrow) * K + lchunk * 8;
  const ushort_t* Ag1 = Ag0 + (size_t)16 * K;
  const ushort_t* Bg0 = B + (size_t)(n0 + rowW + lrow) * K + lchunk * 8;
  const ushort_t* Bg1 = Bg0 + (size_t)16 * K;
  char* lA0 = As + rowW * 64;
  char* lA1 = As + (rowW + 16) * 64;
  char* lB0 = Bs + rowW * 64;
  char* lB1 = Bs + (rowW + 16) * 64;

  const int rA = wm * 64 + (lane & 15);
  const int rB = wn * 64 + (lane & 15);
  const int kq = (lane >> 4) * 16;

  for (int k0 = 0; k0 < K; k0 += 32) {
    async16(Ag0 + k0, lA0);
    async16(Ag1 + k0, lA1);
    async16(Bg0 + k0, lB0);
    async16(Bg1 + k0, lB1);
    __syncthreads();

    bf16x8 af[4], bfr[4];
#pragma unroll
    for (int i = 0; i < 4; ++i) {
      af[i]  = *(const bf16x8*)(As + (rA + i * 16) * 64 + kq);
      bfr[i] = *(const bf16x8*)(Bs + (rB + i * 16) * 64 + kq);
    }
#pragma unroll
    for (int i = 0; i < 4; ++i)
#pragma unroll
      for (int j = 0; j < 4; ++j)
        acc[i][j] = __builtin_amdgcn_mfma_f32_16x16x32_bf16(
            af[i], bfr[j], acc[i][j], 0, 0, 0);
    __syncthreads();
  }

  const int mbase = m0 + wm * 64 + (lane >> 4) * 4;
  const int nbase = n0 + wn * 64 + (lane & 15);
#pragma unroll
  for (int i = 0; i < 4; ++i)
#pragma unroll
    for (int j = 0; j < 4; ++j)
#pragma unroll
      for (int r = 0; r < 4; ++r) {
        const int m = mbase + i * 16 + r;
        const int n = nbase + j * 16;
        const float v = acc[i][j][r];
        if (OUT_BF16)
          ((ushort_t*)C)[(size_t)m * ldc + n] = f2bf(v);
        else
          ((float*)C)[(size_t)m * ldc + n] = v;
      }
}

// ---------------------------------------------------------------------------
// Depthwise causal conv1d (K=4) + bias + SiLU. Input hbcdt bf16 (ld 2432),
// output convo bf16 (ld 2304).
// ---------------------------------------------------------------------------
__global__ __launch_bounds__(256) void conv_silu_kernel(
    const ushort_t* __restrict__ hbcdt, const float* __restrict__ conv_w,
    const float* __restrict__ conv_b, ushort_t* __restrict__ convo) {
  const int idx = blockIdx.x * 256 + threadIdx.x;
  if (idx >= ROWS * CONV_DIM) return;
  const int c   = idx % CONV_DIM;
  const int row = idx / CONV_DIM;
  const int l   = row & (LSEQ - 1);
  float acc = conv_b[c];
  const float* w = conv_w + c * KCONV;
#pragma unroll
  for (int k = 0; k < KCONV; ++k) {
    const int tt = l + k - (KCONV - 1);
    if (tt >= 0)
      acc = fmaf(bf2f(hbcdt[(size_t)(row + k - (KCONV - 1)) * HBCDT_PAD + c]), w[k], acc);
  }
  convo[idx] = f2bf(siluf(acc));
}

// ---------------------------------------------------------------------------
// dt = softplus(dt_raw + dt_bias); dA = exp(-exp(A_log)*dt)
// ---------------------------------------------------------------------------
__global__ __launch_bounds__(256) void dtprep_kernel(
    const ushort_t* __restrict__ hbcdt, const float* __restrict__ dt_bias,
    const float* __restrict__ A_log, float* __restrict__ dt_s,
    float* __restrict__ dA_s) {
  const int idx = blockIdx.x * 256 + threadIdx.x;
  if (idx >= ROWS * NH) return;
  const int h   = idx & (NH - 1);
  const int row = idx >> 5;
  float x = bf2f(hbcdt[(size_t)row * HBCDT_PAD + CONV_DIM + h]) + dt_bias[h];
  float dtv = (x > 20.f) ? x : log1pf(__expf(x));
  dt_s[idx] = dtv;
  dA_s[idx] = __expf(-__expf(A_log[h]) * dtv);
}

// ---------------------------------------------------------------------------
// Chunked scan, pass 1: per-chunk local states (h0 = 0), update only.
// Grid: B*NH*8*NC = 16384 blocks x 256 thr.
// Writes Sloc[b][c][h][p][n] (bf16) and chunkA[b][h][c] (fp32, thread 0).
// ---------------------------------------------------------------------------
#define SU 8
__global__ __launch_bounds__(256) void scan_state_kernel(
    const ushort_t* __restrict__ convo, const float* __restrict__ dt_s,
    const float* __restrict__ dA_s, ushort_t* __restrict__ Sbuf,
    float* __restrict__ chunkA) {
  const int blk = blockIdx.x;
  const int c   = blk & (NC - 1);
  const int pc  = (blk >> 5) & 7;
  const int h   = (blk >> 8) & 31;
  const int b   = (blk >> 13) & 1;
  const int t   = threadIdx.x;
  const int p_local = t >> 5;
  const int nc  = t & 31;
  const int n0  = nc * 4;
  const int p   = pc * 8 + p_local;

  const ushort_t* base = convo + (size_t)b * LSEQ * CONV_DIM;
  const int xoff = h * PDIM + p;

  float s0 = 0.f, s1 = 0.f, s2 = 0.f, s3 = 0.f;
  float prodA = 1.f;

  const int tstart = c * CLEN;
  for (int t0 = tstart; t0 < tstart + CLEN; t0 += SU) {
    ushort_t xs[SU];
    ushort4  Bu[SU];
    float    dts[SU], dAs[SU];
#pragma unroll
    for (int u = 0; u < SU; ++u) {
      const ushort_t* row = base + (size_t)(t0 + u) * CONV_DIM;
      xs[u] = row[xoff];
      Bu[u] = *(const ushort4*)(row + INTER + n0);
      const int ih = (b * LSEQ + t0 + u) * NH + h;
      dts[u] = dt_s[ih];
      dAs[u] = dA_s[ih];
    }
#pragma unroll
    for (int u = 0; u < SU; ++u) {
      const float x   = bf2f(xs[u]);
      const float dtx = dts[u] * x;
      const float dAv = dAs[u];
      prodA *= dAv;
      s0 = fmaf(dAv, s0, dtx * bf2f(Bu[u].x));
      s1 = fmaf(dAv, s1, dtx * bf2f(Bu[u].y));
      s2 = fmaf(dAv, s2, dtx * bf2f(Bu[u].z));
      s3 = fmaf(dAv, s3, dtx * bf2f(Bu[u].w));
    }
  }

  ushort4 o;
  o.x = f2bf(s0); o.y = f2bf(s1); o.z = f2bf(s2); o.w = f2bf(s3);
  const size_t soff = ((((size_t)b * NC + c) * NH + h) * PDIM + p) * NSTATE + n0;
  *(ushort4*)(Sbuf + soff) = o;
  if (t == 0) chunkA[(b * NH + h) * NC + c] = prodA;
}

// ---------------------------------------------------------------------------
// Chunked scan, pass 2: in-place serial combine over chunks.
// ---------------------------------------------------------------------------
__global__ __launch_bounds__(256) void state_combine_kernel(
    ushort_t* __restrict__ Sbuf, const float* __restrict__ chunkA) {
  const int idx = blockIdx.x * 256 + threadIdx.x;
  const int nq = idx & 31;
  const int p  = (idx >> 5) & 63;
  const int h  = (idx >> 11) & 31;
  const int b  = (idx >> 16) & 1;
  const float* ca = chunkA + (b * NH + h) * NC;

  float s0 = 0.f, s1 = 0.f, s2 = 0.f, s3 = 0.f;
#pragma unroll 4
  for (int c = 0; c < NC; ++c) {
    const size_t off = ((((size_t)b * NC + c) * NH + h) * PDIM + p) * NSTATE + nq * 4;
    ushort4 loc = *(const ushort4*)(Sbuf + off);
    ushort4 o;
    o.x = f2bf(s0); o.y = f2bf(s1); o.z = f2bf(s2); o.w = f2bf(s3);
    *(ushort4*)(Sbuf + off) = o;                 // Sin for chunk c
    const float a = ca[c];
    s0 = fmaf(a, s0, bf2f(loc.x));
    s1 = fmaf(a, s1, bf2f(loc.y));
    s2 = fmaf(a, s2, bf2f(loc.z));
    s3 = fmaf(a, s3, bf2f(loc.w));
  }
}

// ---------------------------------------------------------------------------
// SSD Y-kernel (replaces scalar scan_y): per (b,h,c) chunk of Q=128,
//   La[t] = cumsum(-exp(A_log[h])*dt) over chunk
//   G = C @ B^T                       (MFMA, frags direct from global)
//   W[t,s] = (t>=s) ? G*dt[s]*exp(La[t]-La[s]) : 0   -> LDS bf16
//   Y = exp(La[t]) o (C @ Sin^T) + W @ X + D*x
// Grid: B*NH*NC = 2048 blocks x 256 thr (4 waves).
// LDS: XT (X transposed, XOR-swizzled, 16K) + W (128x136 bf16 = 34K) + misc.
// ---------------------------------------------------------------------------
#define WLD 272   // W row stride bytes (128*2 + 16 pad -> 2-way bank conflicts only)
__global__ __launch_bounds__(256) void ssd_y_kernel(
    const ushort_t* __restrict__ convo, const float* __restrict__ dt_s,
    const float* __restrict__ A_log, const float* __restrict__ D_param,
    const ushort_t* __restrict__ Sbuf, ushort_t* __restrict__ ybuf) {
  __shared__ __align__(16) char XT[64 * 256];     // [p][t^sw] bf16
  __shared__ __align__(16) char Wsh[128 * WLD];   // [t][s] bf16, padded rows
  __shared__ float dt_sh[CLEN];
  __shared__ float La[CLEN];

  const int blk = blockIdx.x;
  const int c   = blk & (NC - 1);
  const int h   = (blk >> 5) & 31;
  const int b   = blk >> 10;
  const int t   = threadIdx.x;
  const int lane = t & 63;
  const int wave = t >> 6;

  const size_t crow = (size_t)(b * LSEQ + c * CLEN);

  // ---- stage X transposed into LDS (XOR swizzle on t within 64-t octets) ----
  {
    const int p = lane;
    const int xcol = h * PDIM + p;
#pragma unroll
    for (int oct = 0; oct < 4; ++oct) {
      const int tl0 = wave * 32 + oct * 8;
      unsigned int pk[4];
#pragma unroll
      for (int e = 0; e < 4; ++e) {
        ushort_t v0 = convo[(crow + tl0 + 2 * e) * CONV_DIM + xcol];
        ushort_t v1 = convo[(crow + tl0 + 2 * e + 1) * CONV_DIM + xcol];
        pk[e] = (unsigned int)v0 | ((unsigned int)v1 << 16);
      }
      const int tsw = tl0 ^ ((p & 7) << 3);
      *(uint4*)(XT + p * 256 + tsw * 2) = make_uint4(pk[0], pk[1], pk[2], pk[3]);
    }
  }
  // ---- stage dt for chunk ----
  if (t < CLEN) dt_sh[t] = dt_s[(crow + t) * NH + h];
  __syncthreads();

  // ---- wave 0: inclusive prefix sum of log(dA) = -a*dt ----
  if (wave == 0) {
    const float a = __expf(A_log[h]);
    float v0 = -a * dt_sh[lane];
    float v1 = -a * dt_sh[lane + 64];
#pragma unroll
    for (int off = 1; off < 64; off <<= 1) {
      float u0 = __shfl_up(v0, off);
      float u1 = __shfl_up(v1, off);
      if (lane >= off) { v0 += u0; v1 += u1; }
    }
    const float tot0 = __shfl(v0, 63);
    La[lane]      = v0;
    La[lane + 64] = v1 + tot0;
  }
  __syncthreads();

  // ---- phase 1: G = C @ B^T (per-wave 64x64 tile), then W -> LDS ----
  const int wt = wave & 1;
  const int ws = wave >> 1;
  const bool active = !(wt == 0 && ws == 1);   // strictly-upper tile is all zero

  f32x4 g[4][4];
#pragma unroll
  for (int i = 0; i < 4; ++i)
#pragma unroll
    for (int j = 0; j < 4; ++j) {
      f32x4 z = {0.f, 0.f, 0.f, 0.f};
      g[i][j] = z;
    }

  if (active) {
    for (int k0 = 0; k0 < 4; ++k0) {
      const int koct = k0 * 32 + (lane >> 4) * 8;
      bf16x8 cf[4], bfg[4];
#pragma unroll
      for (int i = 0; i < 4; ++i) {
        const int tg = wt * 64 + i * 16 + (lane & 15);
        cf[i] = *(const bf16x8*)(convo + (crow + tg) * CONV_DIM + INTER + NSTATE + koct);
        const int sg = ws * 64 + i * 16 + (lane & 15);
        bfg[i] = *(const bf16x8*)(convo + (crow + sg) * CONV_DIM + INTER + koct);
      }
#pragma unroll
      for (int i = 0; i < 4; ++i)
#pragma unroll
        for (int j = 0; j < 4; ++j)
          g[i][j] = __builtin_amdgcn_mfma_f32_16x16x32_bf16(cf[i], bfg[j], g[i][j], 0, 0, 0);
    }
  }
#pragma unroll
  for (int i = 0; i < 4; ++i) {
    const int tbase = wt * 64 + i * 16 + ((lane >> 4) << 2);
    float Lat[4];
#pragma unroll
    for (int r = 0; r < 4; ++r) Lat[r] = La[tbase + r];
#pragma unroll
    for (int j = 0; j < 4; ++j) {
      const int sl  = ws * 64 + j * 16 + (lane & 15);
      const float Las = La[sl];
      const float dts = dt_sh[sl];
#pragma unroll
      for (int r = 0; r < 4; ++r) {
        const int tl = tbase + r;
        float val = 0.f;
        if (active && tl >= sl)
          val = g[i][j][r] * dts * __expf(Lat[r] - Las);
        *(ushort_t*)(Wsh + tl * WLD + sl * 2) = f2bf(val);
      }
    }
  }
  __syncthreads();

  // ---- phase 2: Y = exp(La) o (C @ Sin^T) + W @ X ----
  const int yt = wave & 1;        // t-half
  const int yp = wave >> 1;       // p-half (32 p's per wave)
  f32x4 acc[4][2];
#pragma unroll
  for (int i = 0; i < 4; ++i)
#pragma unroll
    for (int j = 0; j < 2; ++j) {
      f32x4 z = {0.f, 0.f, 0.f, 0.f};
      acc[i][j] = z;
    }

  const ushort_t* Sb = Sbuf + (((size_t)b * NC + c) * NH + h) * PDIM * NSTATE;

  // Yinter: C @ Sin^T  (K = N = 128)
  for (int k0 = 0; k0 < 4; ++k0) {
    const int koct = k0 * 32 + (lane >> 4) * 8;
    bf16x8 af[4], sf[2];
#pragma unroll
    for (int i = 0; i < 4; ++i) {
      const int tg = yt * 64 + i * 16 + (lane & 15);
      af[i] = *(const bf16x8*)(convo + (crow + tg) * CONV_DIM + INTER + NSTATE + koct);
    }
#pragma unroll
    for (int j = 0; j < 2; ++j) {
      const int pr = yp * 32 + j * 16 + (lane & 15);
      sf[j] = *(const bf16x8*)(Sb + pr * NSTATE + koct);
    }
#pragma unroll
    for (int i = 0; i < 4; ++i)
#pragma unroll
      for (int j = 0; j < 2; ++j)
        acc[i][j] = __builtin_amdgcn_mfma_f32_16x16x32_bf16(af[i], sf[j], acc[i][j], 0, 0, 0);
  }
  // scale by exp(La[t]) in fp32
#pragma unroll
  for (int i = 0; i < 4; ++i) {
    const int tbase = yt * 64 + i * 16 + ((lane >> 4) << 2);
#pragma unroll
    for (int r = 0; r < 4; ++r) {
      const float e = __expf(La[tbase + r]);
#pragma unroll
      for (int j = 0; j < 2; ++j) acc[i][j][r] *= e;
    }
  }
  // Yintra: W @ X  (K = Q = 128; A from Wsh, B from XT)
  for (int k0 = 0; k0 < 4; ++k0) {
    const int koct = k0 * 32 + (lane >> 4) * 8;
    bf16x8 wf[4], xf[2];
#pragma unroll
    for (int i = 0; i < 4; ++i) {
      const int tl = yt * 64 + i * 16 + (lane & 15);
      wf[i] = *(const bf16x8*)(Wsh + tl * WLD + koct * 2);
    }
#pragma unroll
    for (int j = 0; j < 2; ++j) {
      const int pr  = yp * 32 + j * 16 + (lane & 15);
      const int tsw = koct ^ ((pr & 7) << 3);
      xf[j] = *(const bf16x8*)(XT + pr * 256 + tsw * 2);
    }
#pragma unroll
    for (int i = 0; i < 4; ++i)
#pragma unroll
      for (int j = 0; j < 2; ++j)
        acc[i][j] = __builtin_amdgcn_mfma_f32_16x16x32_bf16(wf[i], xf[j], acc[i][j], 0, 0, 0);
  }

  // ---- epilogue: + D*x, write y ----
  const float Dh = D_param[h];
#pragma unroll
  for (int i = 0; i < 4; ++i) {
    const int tbase = yt * 64 + i * 16 + ((lane >> 4) << 2);
#pragma unroll
    for (int j = 0; j < 2; ++j) {
      const int pr = yp * 32 + j * 16 + (lane & 15);
#pragma unroll
      for (int r = 0; r < 4; ++r) {
        const int tl  = tbase + r;
        const int tsw = tl ^ ((pr & 7) << 3);
        const float x = bf2f(*(const ushort_t*)(XT + pr * 256 + tsw * 2));
        ybuf[(crow + tl) * INTER + h * PDIM + pr] = f2bf(acc[i][j][r] + Dh * x);
      }
    }
  }
}

// ---------------------------------------------------------------------------
// Gated RMSNorm (bf16 in/out, in-place on y).
// ---------------------------------------------------------------------------
__global__ __launch_bounds__(256) void gated_rmsnorm_kernel(
    ushort_t* __restrict__ y, const ushort_t* __restrict__ gate,
    const float* __restrict__ norm_w) {
  const int row = blockIdx.x;
  ushort_t* yr = y + (size_t)row * INTER;
  const ushort_t* gr = gate + (size_t)row * INTER;
  const int t  = threadIdx.x;
  const int i0 = t * 8;

  ushort4 ya = *(const ushort4*)(yr + i0);
  ushort4 yb = *(const ushort4*)(yr + i0 + 4);
  ushort4 ga = *(const ushort4*)(gr + i0);
  ushort4 gb = *(const ushort4*)(gr + i0 + 4);

  float g[8];
  g[0] = bf2f(ya.x) * siluf(bf2f(ga.x));
  g[1] = bf2f(ya.y) * siluf(bf2f(ga.y));
  g[2] = bf2f(ya.z) * siluf(bf2f(ga.z));
  g[3] = bf2f(ya.w) * siluf(bf2f(ga.w));
  g[4] = bf2f(yb.x) * siluf(bf2f(gb.x));
  g[5] = bf2f(yb.y) * siluf(bf2f(gb.y));
  g[6] = bf2f(yb.z) * siluf(bf2f(gb.z));
  g[7] = bf2f(yb.w) * siluf(bf2f(gb.w));

  float ss = 0.f;
#pragma unroll
  for (int i = 0; i < 8; ++i) ss += g[i] * g[i];

  ss += __shfl_xor(ss, 32);
  ss += __shfl_xor(ss, 16);
  ss += __shfl_xor(ss, 8);
  ss += __shfl_xor(ss, 4);
  ss += __shfl_xor(ss, 2);
  ss += __shfl_xor(ss, 1);

  __shared__ float red[4];
  if ((t & 63) == 0) red[t >> 6] = ss;
  __syncthreads();
  const float tot = red[0] + red[1] + red[2] + red[3];
  const float scale = rsqrtf(tot * (1.0f / INTER) + 1e-5f);

  ushort4 o0, o1;
  o0.x = f2bf(g[0] * scale * norm_w[i0 + 0]);
  o0.y = f2bf(g[1] * scale * norm_w[i0 + 1]);
  o0.z = f2bf(g[2] * scale * norm_w[i0 + 2]);
  o0.w = f2bf(g[3] * scale * norm_w[i0 + 3]);
  o1.x = f2bf(g[4] * scale * norm_w[i0 + 4]);
  o1.y = f2bf(g[5] * scale * norm_w[i0 + 5]);
  o1.z = f2bf(g[6] * scale * norm_w[i0 + 6]);
  o1.w = f2bf(g[7] * scale * norm_w[i0 + 7]);
  *(ushort4*)(yr + i0)     = o0;
  *(ushort4*)(yr + i0 + 4) = o1;
}

// ---------------------------------------------------------------------------
// Workspace (~106.4 MB): hbcdt_bf(39.8, aliased by ybuf) | convo(37.7) |
// dt_s/dA_s(2) | Wh_bf(10.0) | Wg_bf(8.4) | Wout_bf(8.4) | chunkA(8KB).
// d_out scratch: [0,33.5MB) gate_bf; [33.5,67MB) hs_bf -> Sbuf (states).
// ---------------------------------------------------------------------------
extern "C" void kernel_launch(void* const* d_in, const int* in_sizes, int n_in,
                              void* d_out, int out_size, void* d_ws, size_t ws_size,
                              hipStream_t stream) {
  const float* hs      = (const float*)d_in[0];
  const float* W_in    = (const float*)d_in[1];
  const float* conv_w  = (const float*)d_in[2];
  const float* conv_b  = (const float*)d_in[3];
  const float* dt_bias = (const float*)d_in[4];
  const float* A_log   = (const float*)d_in[5];
  const float* D_param = (const float*)d_in[6];
  const float* norm_w  = (const float*)d_in[7];
  const float* W_out   = (const float*)d_in[8];
  float* out = (float*)d_out;

  char* ws = (char*)d_ws;
  size_t off = 0;
  ushort_t* hbcdt_bf = (ushort_t*)(ws + off); off += (size_t)ROWS * HBCDT_PAD * 2;
  ushort_t* convo    = (ushort_t*)(ws + off); off += (size_t)ROWS * CONV_DIM * 2;
  float*    dt_s     = (float*)(ws + off);    off += (size_t)ROWS * NH * 4;
  float*    dA_s     = (float*)(ws + off);    off += (size_t)ROWS * NH * 4;
  ushort_t* Wh_bf    = (ushort_t*)(ws + off); off += (size_t)HBCDT_PAD * DMODEL * 2;
  ushort_t* Wg_bf    = (ushort_t*)(ws + off); off += (size_t)DMODEL * DMODEL * 2;
  ushort_t* Wout_bf  = (ushort_t*)(ws + off); off += (size_t)DMODEL * DMODEL * 2;
  float*    chunkA   = (float*)(ws + off);    off += (size_t)B_ * NH * NC * 4;
  ushort_t* ybuf_bf  = hbcdt_bf;                       // alias (hBC_dt dead)

  char* outc = (char*)d_out;
  ushort_t* gate_bf = (ushort_t*)outc;                              // 33.5 MB
  ushort_t* hs_bf   = (ushort_t*)(outc + (size_t)ROWS * INTER * 2); // 33.5 MB
  ushort_t* Sbuf    = hs_bf;   // states overwrite hs_bf after GEMMs consume it

  // 0. conversions
  cvt_f32_bf16<<<(ROWS * DMODEL / 4 + 255) / 256, 256, 0, stream>>>(
      hs, hs_bf, ROWS * DMODEL);
  cvt_Wh<<<(HBCDT_PAD * DMODEL / 4 + 255) / 256, 256, 0, stream>>>(W_in, Wh_bf);
  cvt_f32_bf16<<<(DMODEL * DMODEL / 4 + 255) / 256, 256, 0, stream>>>(
      W_in, Wg_bf, DMODEL * DMODEL);
  cvt_f32_bf16<<<(DMODEL * DMODEL / 4 + 255) / 256, 256, 0, stream>>>(
      W_out, Wout_bf, DMODEL * DMODEL);

  // 1a. hBC_dt = hs @ Wh^T
  {
    dim3 grid(HBCDT_PAD / 128, ROWS / 128);
    gemm_bf16_nt<true><<<grid, 256, 0, stream>>>(
        hs_bf, Wh_bf, hbcdt_bf, ROWS, HBCDT_PAD, DMODEL, HBCDT_PAD);
  }
  // 1b. gate = hs @ Wg^T
  {
    dim3 grid(INTER / 128, ROWS / 128);
    gemm_bf16_nt<true><<<grid, 256, 0, stream>>>(
        hs_bf, Wg_bf, gate_bf, ROWS, INTER, DMODEL, INTER);
  }
  // 2. conv + silu
  conv_silu_kernel<<<(ROWS * CONV_DIM + 255) / 256, 256, 0, stream>>>(
      hbcdt_bf, conv_w, conv_b, convo);
  // 3. dt / dA
  dtprep_kernel<<<(ROWS * NH + 255) / 256, 256, 0, stream>>>(
      hbcdt_bf, dt_bias, A_log, dt_s, dA_s);
  // 4. chunked scan: local states -> combine -> SSD Y (MFMA)
  scan_state_kernel<<<B_ * NH * 8 * NC, 256, 0, stream>>>(
      convo, dt_s, dA_s, Sbuf, chunkA);
  state_combine_kernel<<<(B_ * NH * PDIM * (NSTATE / 4)) / 256, 256, 0, stream>>>(
      Sbuf, chunkA);
  ssd_y_kernel<<<B_ * NH * NC, 256, 0, stream>>>(
      convo, dt_s, A_log, D_param, Sbuf, ybuf_bf);
  // 5. gated rmsnorm (in-place on ybuf_bf)
  gated_rmsnorm_kernel<<<ROWS, 256, 0, stream>>>(ybuf_bf, gate_bf, norm_w);
  // 6. out = g @ W_out^T (fp32, overwrites d_out)
  {
    dim3 grid(DMODEL / 128, ROWS / 128);
    gemm_bf16_nt<false><<<grid, 256, 0, stream>>>(
        ybuf_bf, Wout_bf, out, ROWS, DMODEL, INTER, DMODEL);
  }
}

// Round 8
// 715.571 us; speedup vs baseline: 7.6788x; 1.3700x over previous
//
#include <hip/hip_runtime.h>
#include <cstdint>
#include <cstddef>

// Problem constants
#define B_        2
#define LSEQ      4096
#define DMODEL    2048
#define NH        32
#define PDIM      64
#define NSTATE    128
#define KCONV     4
#define INTER     2048       // NH*PDIM
#define CONV_DIM  2304       // INTER + 2*NSTATE
#define HBCDT     2336       // CONV_DIM + NH
#define HBCDT_PAD 2432       // padded to 19*128 for GEMM tiling
#define ROWS      (B_*LSEQ)  // 8192
#define NC        32         // sequence chunks for the scan
#define CLEN      (LSEQ/NC)  // 128  (= Q)

typedef unsigned short ushort_t;
typedef short bf16x8 __attribute__((ext_vector_type(8)));
typedef float f32x4 __attribute__((ext_vector_type(4)));

__device__ __forceinline__ float siluf(float x) {
  return x / (1.0f + __expf(-x));
}
__device__ __forceinline__ float bf2f(ushort_t u) {
  union { unsigned int i; float f; } v; v.i = ((unsigned int)u) << 16; return v.f;
}
__device__ __forceinline__ ushort_t f2bf(float f) {
  union { float f; unsigned int i; } v; v.f = f;
  unsigned int r = v.i + 0x7fff + ((v.i >> 16) & 1);   // RNE
  return (ushort_t)(r >> 16);
}
__device__ __forceinline__ void async16(const void* g, void* l) {
  __builtin_amdgcn_global_load_lds(
      (const __attribute__((address_space(1))) unsigned int*)g,
      (__attribute__((address_space(3))) unsigned int*)l, 16, 0, 0);
}

// ---------------------------------------------------------------------------
// fp32 -> bf16 conversions
// ---------------------------------------------------------------------------
__global__ __launch_bounds__(256) void cvt_f32_bf16(
    const float* __restrict__ src, ushort_t* __restrict__ dst, int n) {
  const int i = (blockIdx.x * 256 + threadIdx.x) * 4;
  if (i >= n) return;
  float4 v = *(const float4*)(src + i);
  ushort4 o; o.x = f2bf(v.x); o.y = f2bf(v.y); o.z = f2bf(v.z); o.w = f2bf(v.w);
  *(ushort4*)(dst + i) = o;
}

// W_in rows [INTER, INTER+HBCDT) -> bf16 padded to HBCDT_PAD rows (zeros)
__global__ __launch_bounds__(256) void cvt_Wh(
    const float* __restrict__ W_in, ushort_t* __restrict__ dst) {
  const int i = (blockIdx.x * 256 + threadIdx.x) * 4;
  if (i >= HBCDT_PAD * DMODEL) return;
  const int r = i / DMODEL, c = i % DMODEL;
  ushort4 o;
  if (r < HBCDT) {
    float4 v = *(const float4*)(W_in + (size_t)(INTER + r) * DMODEL + c);
    o.x = f2bf(v.x); o.y = f2bf(v.y); o.z = f2bf(v.z); o.w = f2bf(v.w);
  } else {
    o.x = 0; o.y = 0; o.z = 0; o.w = 0;
  }
  *(ushort4*)(dst + i) = o;
}

// ---------------------------------------------------------------------------
// bf16 NT MFMA GEMM: C[m,n] = sum_k A[m,k]*B[n,k]. 128x128 tile, BK=32,
// 4 waves (2x2), each wave 64x64 via 4x4 MFMA 16x16x32 tiles.
// ---------------------------------------------------------------------------
template <bool OUT_BF16>
__global__ __launch_bounds__(256) void gemm_bf16_nt(
    const ushort_t* __restrict__ A, const ushort_t* __restrict__ B,
    void* __restrict__ C, int M, int N, int K, int ldc) {
  __shared__ __align__(16) char smem[16384];
  char* As = smem;            // [128][32] bf16, row stride 64 B
  char* Bs = smem + 8192;
  const int t    = threadIdx.x;
  const int lane = t & 63;
  const int wave = t >> 6;
  const int m0 = blockIdx.y * 128;
  const int n0 = blockIdx.x * 128;
  const int wm = wave & 1;
  const int wn = wave >> 1;

  f32x4 acc[4][4];
#pragma unroll
  for (int i = 0; i < 4; ++i)
#pragma unroll
    for (int j = 0; j < 4; ++j) {
      f32x4 z = {0.f, 0.f, 0.f, 0.f};
      acc[i][j] = z;
    }

  const int rowW   = wave * 32;
  const int lrow   = lane >> 2;
  const int lchunk = lane & 3;
  const ushort_t* Ag0 = A + (size_t)(m0 + rowW + lrow) * K + lchunk * 8;
  const ushort_t* Ag1 = Ag0 + (size_t)16 * K;
  const ushort_t* Bg0 = B + (size_t)(n0 + rowW + lrow) * K + lchunk * 8;
  const ushort_t* Bg1 = Bg0 + (size_t)16 * K;
  char* lA0 = As + rowW * 64;
  char* lA1 = As + (rowW + 16) * 64;
  char* lB0 = Bs + rowW * 64;
  char* lB1 = Bs + (rowW + 16) * 64;

  const int rA = wm * 64 + (lane & 15);
  const int rB = wn * 64 + (lane & 15);
  const int kq = (lane >> 4) * 16;

  for (int k0 = 0; k0 < K; k0 += 32) {
    async16(Ag0 + k0, lA0);
    async16(Ag1 + k0, lA1);
    async16(Bg0 + k0, lB0);
    async16(Bg1 + k0, lB1);
    __syncthreads();

    bf16x8 af[4], bfr[4];
#pragma unroll
    for (int i = 0; i < 4; ++i) {
      af[i]  = *(const bf16x8*)(As + (rA + i * 16) * 64 + kq);
      bfr[i] = *(const bf16x8*)(Bs + (rB + i * 16) * 64 + kq);
    }
#pragma unroll
    for (int i = 0; i < 4; ++i)
#pragma unroll
      for (int j = 0; j < 4; ++j)
        acc[i][j] = __builtin_amdgcn_mfma_f32_16x16x32_bf16(
            af[i], bfr[j], acc[i][j], 0, 0, 0);
    __syncthreads();
  }

  const int mbase = m0 + wm * 64 + (lane >> 4) * 4;
  const int nbase = n0 + wn * 64 + (lane & 15);
#pragma unroll
  for (int i = 0; i < 4; ++i)
#pragma unroll
    for (int j = 0; j < 4; ++j)
#pragma unroll
      for (int r = 0; r < 4; ++r) {
        const int m = mbase + i * 16 + r;
        const int n = nbase + j * 16;
        const float v = acc[i][j][r];
        if (OUT_BF16)
          ((ushort_t*)C)[(size_t)m * ldc + n] = f2bf(v);
        else
          ((float*)C)[(size_t)m * ldc + n] = v;
      }
}

// ---------------------------------------------------------------------------
// Depthwise causal conv1d (K=4) + bias + SiLU. Input hbcdt bf16 (ld 2432),
// output convo bf16 (ld 2304). Additionally writes the B section (c in
// [INTER, INTER+NSTATE)) transposed: BT_g[b][chunk][n][s_local] for the
// MFMA scan-state kernel (G=1: B is head-shared).
// ---------------------------------------------------------------------------
__global__ __launch_bounds__(256) void conv_silu_kernel(
    const ushort_t* __restrict__ hbcdt, const float* __restrict__ conv_w,
    const float* __restrict__ conv_b, ushort_t* __restrict__ convo,
    ushort_t* __restrict__ BT_g) {
  const int idx = blockIdx.x * 256 + threadIdx.x;
  if (idx >= ROWS * CONV_DIM) return;
  const int c   = idx % CONV_DIM;
  const int row = idx / CONV_DIM;
  const int l   = row & (LSEQ - 1);
  float acc = conv_b[c];
  const float* w = conv_w + c * KCONV;
#pragma unroll
  for (int k = 0; k < KCONV; ++k) {
    const int tt = l + k - (KCONV - 1);
    if (tt >= 0)
      acc = fmaf(bf2f(hbcdt[(size_t)(row + k - (KCONV - 1)) * HBCDT_PAD + c]), w[k], acc);
  }
  const ushort_t v = f2bf(siluf(acc));
  convo[idx] = v;
  if (c >= INTER && c < INTER + NSTATE) {
    const int n   = c - INTER;
    const int bb  = row >> 12;        // / LSEQ
    const int cch = l >> 7;           // / CLEN
    const int sl  = l & (CLEN - 1);
    BT_g[(((size_t)bb * NC + cch) * NSTATE + n) * CLEN + sl] = v;
  }
}

// ---------------------------------------------------------------------------
// dt = softplus(dt_raw + dt_bias)
// ---------------------------------------------------------------------------
__global__ __launch_bounds__(256) void dtprep_kernel(
    const ushort_t* __restrict__ hbcdt, const float* __restrict__ dt_bias,
    float* __restrict__ dt_s) {
  const int idx = blockIdx.x * 256 + threadIdx.x;
  if (idx >= ROWS * NH) return;
  const int h   = idx & (NH - 1);
  const int row = idx >> 5;
  float x = bf2f(hbcdt[(size_t)row * HBCDT_PAD + CONV_DIM + h]) + dt_bias[h];
  dt_s[idx] = (x > 20.f) ? x : log1pf(__expf(x));
}

// ---------------------------------------------------------------------------
// Chunked scan, pass 1 (MFMA form): per (b,h,c),
//   La = cumsum(-exp(A_log[h])*dt);  wgt[s] = dt_s * exp(La_end - La_s)
//   S_loc[p][n] = sum_s (x_s[p]*wgt[s]) * B_s[n]   -> NT MFMA, K=s=128
//   chunkA = exp(La_end)
// Grid: B*NH*NC = 2048 blocks x 256 thr (4 waves; wave w -> p rows w*16..+16).
// ---------------------------------------------------------------------------
#define XLD 272   // Xw^T row stride bytes (128*2 + 16 pad -> 2-way conflicts only)
__global__ __launch_bounds__(256) void scan_state_kernel(
    const ushort_t* __restrict__ convo, const float* __restrict__ dt_s,
    const float* __restrict__ A_log, const ushort_t* __restrict__ BT_g,
    ushort_t* __restrict__ Sbuf, float* __restrict__ chunkA) {
  __shared__ __align__(16) char XwT[64 * XLD];   // [p][s] bf16, weighted
  __shared__ float dt_sh[CLEN];
  __shared__ float wgt[CLEN];

  const int blk = blockIdx.x;
  const int c   = blk & (NC - 1);
  const int h   = (blk >> 5) & 31;
  const int b   = blk >> 10;
  const int t   = threadIdx.x;
  const int lane = t & 63;
  const int wave = t >> 6;
  const size_t crow = (size_t)(b * LSEQ + c * CLEN);

  if (t < CLEN) dt_sh[t] = dt_s[(crow + t) * NH + h];
  __syncthreads();

  if (wave == 0) {
    const float a = __expf(A_log[h]);
    float v0 = -a * dt_sh[lane];
    float v1 = -a * dt_sh[lane + 64];
#pragma unroll
    for (int off = 1; off < 64; off <<= 1) {
      float u0 = __shfl_up(v0, off);
      float u1 = __shfl_up(v1, off);
      if (lane >= off) { v0 += u0; v1 += u1; }
    }
    const float tot0 = __shfl(v0, 63);
    const float La0  = v0;
    const float La1  = v1 + tot0;
    const float Lend = __shfl(v1, 63) + tot0;
    wgt[lane]      = dt_sh[lane]      * __expf(Lend - La0);
    wgt[lane + 64] = dt_sh[lane + 64] * __expf(Lend - La1);
    if (lane == 0) chunkA[(b * NH + h) * NC + c] = __expf(Lend);
  }
  __syncthreads();

  // stage weighted Xw^T: thread lane = p, wave covers t in [wave*32, +32)
  {
    const int p = lane;
    const int xcol = h * PDIM + p;
#pragma unroll
    for (int oct = 0; oct < 4; ++oct) {
      const int t0 = wave * 32 + oct * 8;
      unsigned int pk[4];
#pragma unroll
      for (int e = 0; e < 4; ++e) {
        const float f0 = bf2f(convo[(crow + t0 + 2*e)     * CONV_DIM + xcol]) * wgt[t0 + 2*e];
        const float f1 = bf2f(convo[(crow + t0 + 2*e + 1) * CONV_DIM + xcol]) * wgt[t0 + 2*e + 1];
        pk[e] = (unsigned int)f2bf(f0) | ((unsigned int)f2bf(f1) << 16);
      }
      *(uint4*)(XwT + p * XLD + t0 * 2) = make_uint4(pk[0], pk[1], pk[2], pk[3]);
    }
  }
  __syncthreads();

  // MFMA: S_loc[p][n], A = Xw^T (LDS), B = BT_g (global, L2-hot)
  f32x4 acc[8];
#pragma unroll
  for (int j = 0; j < 8; ++j) {
    f32x4 z = {0.f, 0.f, 0.f, 0.f};
    acc[j] = z;
  }
  const int rowA = wave * 16 + (lane & 15);
  const int koff = (lane >> 4) * 8;
  const ushort_t* Bt = BT_g + ((size_t)b * NC + c) * NSTATE * CLEN;
#pragma unroll
  for (int k0 = 0; k0 < 4; ++k0) {
    bf16x8 af = *(const bf16x8*)(XwT + rowA * XLD + (k0 * 32 + koff) * 2);
#pragma unroll
    for (int j = 0; j < 8; ++j) {
      bf16x8 bfx = *(const bf16x8*)(Bt + (size_t)(j * 16 + (lane & 15)) * CLEN + k0 * 32 + koff);
      acc[j] = __builtin_amdgcn_mfma_f32_16x16x32_bf16(af, bfx, acc[j], 0, 0, 0);
    }
  }

  ushort_t* Sb = Sbuf + (((size_t)b * NC + c) * NH + h) * (PDIM * NSTATE);
  const int prow = wave * 16 + (lane >> 4) * 4;
  const int ncol = lane & 15;
#pragma unroll
  for (int j = 0; j < 8; ++j)
#pragma unroll
    for (int r = 0; r < 4; ++r)
      Sb[(size_t)(prow + r) * NSTATE + j * 16 + ncol] = f2bf(acc[j][r]);
}

// ---------------------------------------------------------------------------
// Chunked scan, pass 2: in-place serial combine over chunks.
// ---------------------------------------------------------------------------
__global__ __launch_bounds__(256) void state_combine_kernel(
    ushort_t* __restrict__ Sbuf, const float* __restrict__ chunkA) {
  const int idx = blockIdx.x * 256 + threadIdx.x;
  const int nq = idx & 31;
  const int p  = (idx >> 5) & 63;
  const int h  = (idx >> 11) & 31;
  const int b  = (idx >> 16) & 1;
  const float* ca = chunkA + (b * NH + h) * NC;

  float s0 = 0.f, s1 = 0.f, s2 = 0.f, s3 = 0.f;
#pragma unroll 4
  for (int c = 0; c < NC; ++c) {
    const size_t off = ((((size_t)b * NC + c) * NH + h) * PDIM + p) * NSTATE + nq * 4;
    ushort4 loc = *(const ushort4*)(Sbuf + off);
    ushort4 o;
    o.x = f2bf(s0); o.y = f2bf(s1); o.z = f2bf(s2); o.w = f2bf(s3);
    *(ushort4*)(Sbuf + off) = o;                 // Sin for chunk c
    const float a = ca[c];
    s0 = fmaf(a, s0, bf2f(loc.x));
    s1 = fmaf(a, s1, bf2f(loc.y));
    s2 = fmaf(a, s2, bf2f(loc.z));
    s3 = fmaf(a, s3, bf2f(loc.w));
  }
}

// ---------------------------------------------------------------------------
// SSD Y-kernel: per (b,h,c) chunk of Q=128,
//   La[t] = cumsum(-exp(A_log[h])*dt) over chunk
//   G = C @ B^T;  W[t,s] = (t>=s) ? G*dt[s]*exp(La[t]-La[s]) : 0  -> LDS bf16
//   Y = exp(La[t]) o (C @ Sin^T) + W @ X + D*x
// Grid: B*NH*NC = 2048 blocks x 256 thr (4 waves).
// ---------------------------------------------------------------------------
#define WLD 272   // W row stride bytes (128*2 + 16 pad -> 2-way bank conflicts only)
__global__ __launch_bounds__(256) void ssd_y_kernel(
    const ushort_t* __restrict__ convo, const float* __restrict__ dt_s,
    const float* __restrict__ A_log, const float* __restrict__ D_param,
    const ushort_t* __restrict__ Sbuf, ushort_t* __restrict__ ybuf) {
  __shared__ __align__(16) char XT[64 * 256];     // [p][t^sw] bf16
  __shared__ __align__(16) char Wsh[128 * WLD];   // [t][s] bf16, padded rows
  __shared__ float dt_sh[CLEN];
  __shared__ float La[CLEN];

  const int blk = blockIdx.x;
  const int c   = blk & (NC - 1);
  const int h   = (blk >> 5) & 31;
  const int b   = blk >> 10;
  const int t   = threadIdx.x;
  const int lane = t & 63;
  const int wave = t >> 6;

  const size_t crow = (size_t)(b * LSEQ + c * CLEN);

  // ---- stage X transposed into LDS (XOR swizzle on t within 64-t octets) ----
  {
    const int p = lane;
    const int xcol = h * PDIM + p;
#pragma unroll
    for (int oct = 0; oct < 4; ++oct) {
      const int tl0 = wave * 32 + oct * 8;
      unsigned int pk[4];
#pragma unroll
      for (int e = 0; e < 4; ++e) {
        ushort_t v0 = convo[(crow + tl0 + 2 * e) * CONV_DIM + xcol];
        ushort_t v1 = convo[(crow + tl0 + 2 * e + 1) * CONV_DIM + xcol];
        pk[e] = (unsigned int)v0 | ((unsigned int)v1 << 16);
      }
      const int tsw = tl0 ^ ((p & 7) << 3);
      *(uint4*)(XT + p * 256 + tsw * 2) = make_uint4(pk[0], pk[1], pk[2], pk[3]);
    }
  }
  // ---- stage dt for chunk ----
  if (t < CLEN) dt_sh[t] = dt_s[(crow + t) * NH + h];
  __syncthreads();

  // ---- wave 0: inclusive prefix sum of log(dA) = -a*dt ----
  if (wave == 0) {
    const float a = __expf(A_log[h]);
    float v0 = -a * dt_sh[lane];
    float v1 = -a * dt_sh[lane + 64];
#pragma unroll
    for (int off = 1; off < 64; off <<= 1) {
      float u0 = __shfl_up(v0, off);
      float u1 = __shfl_up(v1, off);
      if (lane >= off) { v0 += u0; v1 += u1; }
    }
    const float tot0 = __shfl(v0, 63);
    La[lane]      = v0;
    La[lane + 64] = v1 + tot0;
  }
  __syncthreads();

  // ---- phase 1: G = C @ B^T (per-wave 64x64 tile), then W -> LDS ----
  const int wt = wave & 1;
  const int ws = wave >> 1;
  const bool active = !(wt == 0 && ws == 1);   // strictly-upper tile is all zero

  f32x4 g[4][4];
#pragma unroll
  for (int i = 0; i < 4; ++i)
#pragma unroll
    for (int j = 0; j < 4; ++j) {
      f32x4 z = {0.f, 0.f, 0.f, 0.f};
      g[i][j] = z;
    }

  if (active) {
    for (int k0 = 0; k0 < 4; ++k0) {
      const int koct = k0 * 32 + (lane >> 4) * 8;
      bf16x8 cf[4], bfg[4];
#pragma unroll
      for (int i = 0; i < 4; ++i) {
        const int tg = wt * 64 + i * 16 + (lane & 15);
        cf[i] = *(const bf16x8*)(convo + (crow + tg) * CONV_DIM + INTER + NSTATE + koct);
        const int sg = ws * 64 + i * 16 + (lane & 15);
        bfg[i] = *(const bf16x8*)(convo + (crow + sg) * CONV_DIM + INTER + koct);
      }
#pragma unroll
      for (int i = 0; i < 4; ++i)
#pragma unroll
        for (int j = 0; j < 4; ++j)
          g[i][j] = __builtin_amdgcn_mfma_f32_16x16x32_bf16(cf[i], bfg[j], g[i][j], 0, 0, 0);
    }
  }
#pragma unroll
  for (int i = 0; i < 4; ++i) {
    const int tbase = wt * 64 + i * 16 + ((lane >> 4) << 2);
    float Lat[4];
#pragma unroll
    for (int r = 0; r < 4; ++r) Lat[r] = La[tbase + r];
#pragma unroll
    for (int j = 0; j < 4; ++j) {
      const int sl  = ws * 64 + j * 16 + (lane & 15);
      const float Las = La[sl];
      const float dts = dt_sh[sl];
#pragma unroll
      for (int r = 0; r < 4; ++r) {
        const int tl = tbase + r;
        float val = 0.f;
        if (active && tl >= sl)
          val = g[i][j][r] * dts * __expf(Lat[r] - Las);
        *(ushort_t*)(Wsh + tl * WLD + sl * 2) = f2bf(val);
      }
    }
  }
  __syncthreads();

  // ---- phase 2: Y = exp(La) o (C @ Sin^T) + W @ X ----
  const int yt = wave & 1;        // t-half
  const int yp = wave >> 1;       // p-half (32 p's per wave)
  f32x4 acc[4][2];
#pragma unroll
  for (int i = 0; i < 4; ++i)
#pragma unroll
    for (int j = 0; j < 2; ++j) {
      f32x4 z = {0.f, 0.f, 0.f, 0.f};
      acc[i][j] = z;
    }

  const ushort_t* Sb = Sbuf + (((size_t)b * NC + c) * NH + h) * PDIM * NSTATE;

  // Yinter: C @ Sin^T  (K = N = 128)
  for (int k0 = 0; k0 < 4; ++k0) {
    const int koct = k0 * 32 + (lane >> 4) * 8;
    bf16x8 af[4], sf[2];
#pragma unroll
    for (int i = 0; i < 4; ++i) {
      const int tg = yt * 64 + i * 16 + (lane & 15);
      af[i] = *(const bf16x8*)(convo + (crow + tg) * CONV_DIM + INTER + NSTATE + koct);
    }
#pragma unroll
    for (int j = 0; j < 2; ++j) {
      const int pr = yp * 32 + j * 16 + (lane & 15);
      sf[j] = *(const bf16x8*)(Sb + pr * NSTATE + koct);
    }
#pragma unroll
    for (int i = 0; i < 4; ++i)
#pragma unroll
      for (int j = 0; j < 2; ++j)
        acc[i][j] = __builtin_amdgcn_mfma_f32_16x16x32_bf16(af[i], sf[j], acc[i][j], 0, 0, 0);
  }
  // scale by exp(La[t]) in fp32
#pragma unroll
  for (int i = 0; i < 4; ++i) {
    const int tbase = yt * 64 + i * 16 + ((lane >> 4) << 2);
#pragma unroll
    for (int r = 0; r < 4; ++r) {
      const float e = __expf(La[tbase + r]);
#pragma unroll
      for (int j = 0; j < 2; ++j) acc[i][j][r] *= e;
    }
  }
  // Yintra: W @ X  (K = Q = 128; A from Wsh, B from XT)
  for (int k0 = 0; k0 < 4; ++k0) {
    const int koct = k0 * 32 + (lane >> 4) * 8;
    bf16x8 wf[4], xf[2];
#pragma unroll
    for (int i = 0; i < 4; ++i) {
      const int tl = yt * 64 + i * 16 + (lane & 15);
      wf[i] = *(const bf16x8*)(Wsh + tl * WLD + koct * 2);
    }
#pragma unroll
    for (int j = 0; j < 2; ++j) {
      const int pr  = yp * 32 + j * 16 + (lane & 15);
      const int tsw = koct ^ ((pr & 7) << 3);
      xf[j] = *(const bf16x8*)(XT + pr * 256 + tsw * 2);
    }
#pragma unroll
    for (int i = 0; i < 4; ++i)
#pragma unroll
      for (int j = 0; j < 2; ++j)
        acc[i][j] = __builtin_amdgcn_mfma_f32_16x16x32_bf16(wf[i], xf[j], acc[i][j], 0, 0, 0);
  }

  // ---- epilogue: + D*x, write y ----
  const float Dh = D_param[h];
#pragma unroll
  for (int i = 0; i < 4; ++i) {
    const int tbase = yt * 64 + i * 16 + ((lane >> 4) << 2);
#pragma unroll
    for (int j = 0; j < 2; ++j) {
      const int pr = yp * 32 + j * 16 + (lane & 15);
#pragma unroll
      for (int r = 0; r < 4; ++r) {
        const int tl  = tbase + r;
        const int tsw = tl ^ ((pr & 7) << 3);
        const float x = bf2f(*(const ushort_t*)(XT + pr * 256 + tsw * 2));
        ybuf[(crow + tl) * INTER + h * PDIM + pr] = f2bf(acc[i][j][r] + Dh * x);
      }
    }
  }
}

// ---------------------------------------------------------------------------
// Gated RMSNorm (bf16 in/out, in-place on y).
// ---------------------------------------------------------------------------
__global__ __launch_bounds__(256) void gated_rmsnorm_kernel(
    ushort_t* __restrict__ y, const ushort_t* __restrict__ gate,
    const float* __restrict__ norm_w) {
  const int row = blockIdx.x;
  ushort_t* yr = y + (size_t)row * INTER;
  const ushort_t* gr = gate + (size_t)row * INTER;
  const int t  = threadIdx.x;
  const int i0 = t * 8;

  ushort4 ya = *(const ushort4*)(yr + i0);
  ushort4 yb = *(const ushort4*)(yr + i0 + 4);
  ushort4 ga = *(const ushort4*)(gr + i0);
  ushort4 gb = *(const ushort4*)(gr + i0 + 4);

  float g[8];
  g[0] = bf2f(ya.x) * siluf(bf2f(ga.x));
  g[1] = bf2f(ya.y) * siluf(bf2f(ga.y));
  g[2] = bf2f(ya.z) * siluf(bf2f(ga.z));
  g[3] = bf2f(ya.w) * siluf(bf2f(ga.w));
  g[4] = bf2f(yb.x) * siluf(bf2f(gb.x));
  g[5] = bf2f(yb.y) * siluf(bf2f(gb.y));
  g[6] = bf2f(yb.z) * siluf(bf2f(gb.z));
  g[7] = bf2f(yb.w) * siluf(bf2f(gb.w));

  float ss = 0.f;
#pragma unroll
  for (int i = 0; i < 8; ++i) ss += g[i] * g[i];

  ss += __shfl_xor(ss, 32);
  ss += __shfl_xor(ss, 16);
  ss += __shfl_xor(ss, 8);
  ss += __shfl_xor(ss, 4);
  ss += __shfl_xor(ss, 2);
  ss += __shfl_xor(ss, 1);

  __shared__ float red[4];
  if ((t & 63) == 0) red[t >> 6] = ss;
  __syncthreads();
  const float tot = red[0] + red[1] + red[2] + red[3];
  const float scale = rsqrtf(tot * (1.0f / INTER) + 1e-5f);

  ushort4 o0, o1;
  o0.x = f2bf(g[0] * scale * norm_w[i0 + 0]);
  o0.y = f2bf(g[1] * scale * norm_w[i0 + 1]);
  o0.z = f2bf(g[2] * scale * norm_w[i0 + 2]);
  o0.w = f2bf(g[3] * scale * norm_w[i0 + 3]);
  o1.x = f2bf(g[4] * scale * norm_w[i0 + 4]);
  o1.y = f2bf(g[5] * scale * norm_w[i0 + 5]);
  o1.z = f2bf(g[6] * scale * norm_w[i0 + 6]);
  o1.w = f2bf(g[7] * scale * norm_w[i0 + 7]);
  *(ushort4*)(yr + i0)     = o0;
  *(ushort4*)(yr + i0 + 4) = o1;
}

// ---------------------------------------------------------------------------
// Workspace (~107.4 MB): hbcdt_bf(39.8, aliased by ybuf) | convo(37.7) |
// dt_s(1) | Wh_bf(10.0) | Wg_bf(8.4) | Wout_bf(8.4) | chunkA(8KB) | BT_g(2).
// d_out scratch: [0,33.5MB) gate_bf; [33.5,67MB) hs_bf -> Sbuf (states).
// ---------------------------------------------------------------------------
extern "C" void kernel_launch(void* const* d_in, const int* in_sizes, int n_in,
                              void* d_out, int out_size, void* d_ws, size_t ws_size,
                              hipStream_t stream) {
  const float* hs      = (const float*)d_in[0];
  const float* W_in    = (const float*)d_in[1];
  const float* conv_w  = (const float*)d_in[2];
  const float* conv_b  = (const float*)d_in[3];
  const float* dt_bias = (const float*)d_in[4];
  const float* A_log   = (const float*)d_in[5];
  const float* D_param = (const float*)d_in[6];
  const float* norm_w  = (const float*)d_in[7];
  const float* W_out   = (const float*)d_in[8];
  float* out = (float*)d_out;

  char* ws = (char*)d_ws;
  size_t off = 0;
  ushort_t* hbcdt_bf = (ushort_t*)(ws + off); off += (size_t)ROWS * HBCDT_PAD * 2;
  ushort_t* convo    = (ushort_t*)(ws + off); off += (size_t)ROWS * CONV_DIM * 2;
  float*    dt_s     = (float*)(ws + off);    off += (size_t)ROWS * NH * 4;
  ushort_t* Wh_bf    = (ushort_t*)(ws + off); off += (size_t)HBCDT_PAD * DMODEL * 2;
  ushort_t* Wg_bf    = (ushort_t*)(ws + off); off += (size_t)DMODEL * DMODEL * 2;
  ushort_t* Wout_bf  = (ushort_t*)(ws + off); off += (size_t)DMODEL * DMODEL * 2;
  float*    chunkA   = (float*)(ws + off);    off += (size_t)B_ * NH * NC * 4;
  ushort_t* BT_g     = (ushort_t*)(ws + off); off += (size_t)B_ * NC * NSTATE * CLEN * 2;
  ushort_t* ybuf_bf  = hbcdt_bf;                       // alias (hBC_dt dead)

  char* outc = (char*)d_out;
  ushort_t* gate_bf = (ushort_t*)outc;                              // 33.5 MB
  ushort_t* hs_bf   = (ushort_t*)(outc + (size_t)ROWS * INTER * 2); // 33.5 MB
  ushort_t* Sbuf    = hs_bf;   // states overwrite hs_bf after GEMMs consume it

  // 0. conversions
  cvt_f32_bf16<<<(ROWS * DMODEL / 4 + 255) / 256, 256, 0, stream>>>(
      hs, hs_bf, ROWS * DMODEL);
  cvt_Wh<<<(HBCDT_PAD * DMODEL / 4 + 255) / 256, 256, 0, stream>>>(W_in, Wh_bf);
  cvt_f32_bf16<<<(DMODEL * DMODEL / 4 + 255) / 256, 256, 0, stream>>>(
      W_in, Wg_bf, DMODEL * DMODEL);
  cvt_f32_bf16<<<(DMODEL * DMODEL / 4 + 255) / 256, 256, 0, stream>>>(
      W_out, Wout_bf, DMODEL * DMODEL);

  // 1a. hBC_dt = hs @ Wh^T
  {
    dim3 grid(HBCDT_PAD / 128, ROWS / 128);
    gemm_bf16_nt<true><<<grid, 256, 0, stream>>>(
        hs_bf, Wh_bf, hbcdt_bf, ROWS, HBCDT_PAD, DMODEL, HBCDT_PAD);
  }
  // 1b. gate = hs @ Wg^T
  {
    dim3 grid(INTER / 128, ROWS / 128);
    gemm_bf16_nt<true><<<grid, 256, 0, stream>>>(
        hs_bf, Wg_bf, gate_bf, ROWS, INTER, DMODEL, INTER);
  }
  // 2. conv + silu (+ transposed B copy for scan-state MFMA)
  conv_silu_kernel<<<(ROWS * CONV_DIM + 255) / 256, 256, 0, stream>>>(
      hbcdt_bf, conv_w, conv_b, convo, BT_g);
  // 3. dt
  dtprep_kernel<<<(ROWS * NH + 255) / 256, 256, 0, stream>>>(
      hbcdt_bf, dt_bias, dt_s);
  // 4. chunked scan: MFMA local states -> combine -> SSD Y (MFMA)
  scan_state_kernel<<<B_ * NH * NC, 256, 0, stream>>>(
      convo, dt_s, A_log, BT_g, Sbuf, chunkA);
  state_combine_kernel<<<(B_ * NH * PDIM * (NSTATE / 4)) / 256, 256, 0, stream>>>(
      Sbuf, chunkA);
  ssd_y_kernel<<<B_ * NH * NC, 256, 0, stream>>>(
      convo, dt_s, A_log, D_param, Sbuf, ybuf_bf);
  // 5. gated rmsnorm (in-place on ybuf_bf)
  gated_rmsnorm_kernel<<<ROWS, 256, 0, stream>>>(ybuf_bf, gate_bf, norm_w);
  // 6. out = g @ W_out^T (fp32, overwrites d_out)
  {
    dim3 grid(DMODEL / 128, ROWS / 128);
    gemm_bf16_nt<false><<<grid, 256, 0, stream>>>(
        ybuf_bf, Wout_bf, out, ROWS, DMODEL, INTER, DMODEL);
  }
}